// Round 7
// baseline (240.401 us; speedup 1.0000x reference)
//
#include <hip/hip_runtime.h>
#include <math.h>

#define HEADS 8
#define HIDC  32
#define MODES 8
#define IN_CH 4
#define SEQ   32
#define NS    64      // B*SEQ samples
#define HD    256     // HEADS*HIDC
#define NM    64      // MODES*MODES
#define NPIX  4096    // 64*64
#define TWO_PI_D 6.283185307179586476925286766559

__device__ __forceinline__ float2 f2(float a, float b){ return make_float2(a,b); }

// ---------------------------------------------------------------------------
// K0: twiddle table Etab[a][b] = (cos,sin)(2*pi*((a*b)&63)/64). Built once.
// ---------------------------------------------------------------------------
__global__ void twiddle_kernel(float2* __restrict__ Etab){
  int t = threadIdx.x;                // 512 threads
  int a = t >> 3, b = t & 7;
  double sv, cv; sincos(TWO_PI_D * ((a*b) & 63) / 64.0, &sv, &cv);
  Etab[t] = f2((float)cv, (float)sv);
}

// ---------------------------------------------------------------------------
// K1: partial forward DFT of v: per field [64][64] -> 8x8 low modes.
// 512 threads (1 block/CU; more waves inside the resident block).
// ---------------------------------------------------------------------------
__global__ __launch_bounds__(512) void fwd_dft_kernel(const float* __restrict__ src,
                                                      const float2* __restrict__ Etab,
                                                      float2* __restrict__ dst){
  int f = blockIdx.x, tid = threadIdx.x;
  __shared__ float  s_fld[64*68];
  __shared__ float2 s_e[64][8];
  __shared__ float2 s_a1[64][8];
  if (tid < 512) ((float2*)s_e)[tid] = Etab[tid];
  const float4* f4 = (const float4*)(src + (size_t)f*NPIX);
  for (int k = tid; k < 1024; k += 512){
    float4 v = f4[k];
    int y = k >> 4, x4 = (k & 15)*4;
    float* row = &s_fld[y*68 + x4];
    row[0]=v.x; row[1]=v.y; row[2]=v.z; row[3]=v.w;
  }
  __syncthreads();
  {
    int o = tid;            // 512 items, one each
    int y = o >> 3, kx = o & 7;
    const float4* row = (const float4*)&s_fld[y*68];
    float sr = 0.f, si = 0.f;
    for (int x4 = 0; x4 < 16; ++x4){
      float4 v = row[x4];
      int xb = x4*4;
      float2 c0 = s_e[xb+0][kx], c1 = s_e[xb+1][kx];
      float2 c2 = s_e[xb+2][kx], c3 = s_e[xb+3][kx];
      sr += v.x*c0.x + v.y*c1.x + v.z*c2.x + v.w*c3.x;
      si -= v.x*c0.y + v.y*c1.y + v.z*c2.y + v.w*c3.y;
    }
    s_a1[y][kx] = f2(sr, si);
  }
  __syncthreads();
  if (tid < 64){
    int ky = tid >> 3, kx = tid & 7;
    float sr = 0.f, si = 0.f;
    for (int y = 0; y < 64; ++y){
      float2 a = s_a1[y][kx];
      float2 cs = s_e[y][ky];
      sr += a.x*cs.x + a.y*cs.y;
      si += a.y*cs.x - a.x*cs.y;
    }
    dst[(size_t)f*NM + tid] = f2(sr, si);
  }
}

// ---------------------------------------------------------------------------
// K2: weight Grams, block per mode m; G2 pre-scaled by Parseval weight.
// ---------------------------------------------------------------------------
__global__ __launch_bounds__(256) void gram_kernel(const float* __restrict__ qwr, const float* __restrict__ qwi,
                                                   const float* __restrict__ kwr, const float* __restrict__ kwi,
                                                   float2* __restrict__ G2, float* __restrict__ Gdc){
  int m = blockIdx.x, tid = threadIdx.x;
  __shared__ float qsr[4][257], qsi[4][257], ksr[4][257], ksi[4][257];
  for (int k = tid; k < 1024; k += 256){
    int i = k >> 8, c = k & 255;
    size_t a = ((size_t)(i*256 + c))*64 + m;
    qsr[i][c] = qwr[a]; qsi[i][c] = qwi[a];
    ksr[i][c] = kwr[a]; ksi[i][c] = kwi[a];
  }
  __syncthreads();
  int kx = m & 7, ky = m >> 3;
  float w = (kx >= 1) ? 2.0f : ((ky >= 1) ? 0.5f : 0.0f);
  for (int e = tid; e < 1024; e += 256){
    int P = e >> 7, T = (e >> 4) & 7, i = (e >> 2) & 3, j = e & 3;
    float grr=0.f, gri=0.f, gir=0.f, gii=0.f;
    for (int d = 0; d < 32; ++d){
      float ar = qsr[i][P*32+d], ai = qsi[i][P*32+d];
      float br = ksr[j][T*32+d], bi = ksi[j][T*32+d];
      grr += ar*br; gri += ar*bi; gir += ai*br; gii += ai*bi;
    }
    G2[(size_t)(((m*8+P)*4+i)*4+j)*8 + T] = f2(w*(grr+gii), w*(gir-gri));
    if (m == 0){
      int o = ((P*4+i)*4+j)*8 + T;
      Gdc[o] = grr; Gdc[1024+o] = gri; Gdc[2048+o] = gir; Gdc[3072+o] = gii;
    }
  }
}

// ---------------------------------------------------------------------------
// K3: attention logits via Parseval + softmax -> A.
// ---------------------------------------------------------------------------
__global__ __launch_bounds__(256) void attn_kernel(const float2* __restrict__ Vf,
                                                   const float2* __restrict__ G2,
                                                   const float* __restrict__ Gdc,
                                                   float* __restrict__ A){
  int bx = blockIdx.x;                 // (b<<8)|(hh<<5)|s
  int s = bx & 31;
  int base = ((bx >> 8) * 32) + (((bx >> 5) & 7) * 4);
  int tid = threadIdx.x;
  int t = tid & 31, mc = tid >> 5;
  __shared__ float2 s_vf[4][IN_CH][64];
  __shared__ float  s_part[8][33];
  for (int k = tid; k < 4*IN_CH*64; k += 256){
    int m = k & 63, c = (k>>6)&3, smp = k>>8;
    s_vf[smp][c][m] = Vf[((size_t)(base+smp)*IN_CH + c)*NM + m];
  }
  __syncthreads();
  int sg = s >> 3, P = s & 7;
  int tg = t >> 3, T = t & 7;
  float acc = 0.f;
  for (int mm = 0; mm < 8; ++mm){
    int m = mc*8 + mm;
    const float2* g = G2 + (size_t)((m*8+P)*16)*8 + T;
    float sub = 0.f;
    for (int i = 0; i < 4; ++i){
      float2 a = s_vf[sg][i][m];
      for (int j = 0; j < 4; ++j){
        float2 b = s_vf[tg][j][m];
        float zr = a.x*b.x + a.y*b.y;
        float zi = a.y*b.x - a.x*b.y;
        float2 gv = g[(size_t)(i*4+j)*8];
        sub += zr*gv.x - zi*gv.y;
      }
    }
    acc += sub;
  }
  if (mc == 0){
    float sub = 0.f;
    for (int i = 0; i < 4; ++i){
      float2 a = s_vf[sg][i][0];
      for (int j = 0; j < 4; ++j){
        float2 b = s_vf[tg][j][0];
        int o = ((P*4+i)*4+j)*8 + T;
        sub += a.x*b.x*Gdc[o] - a.x*b.y*Gdc[1024+o]
             - a.y*b.x*Gdc[2048+o] + a.y*b.y*Gdc[3072+o];
      }
    }
    acc += sub;
  }
  s_part[mc][t] = acc;
  __syncthreads();
  if (tid < 32){
    float l2 = 0.f;
    for (int k = 0; k < 8; ++k) l2 += s_part[k][tid];
    l2 *= 0.5f / (4096.0f * 4096.0f);
    float mx = l2;
    for (int off = 16; off; off >>= 1) mx = fmaxf(mx, __shfl_xor(mx, off, 32));
    float e = expf(l2 - mx);
    float sm = e;
    for (int off = 16; off; off >>= 1) sm += __shfl_xor(sm, off, 32);
    A[(size_t)bx*32 + tid] = e / sm;
  }
}

// ---------------------------------------------------------------------------
// K3b: transpose vw -> vwT[m][c][i] float2 (coalesced reads).
// ---------------------------------------------------------------------------
__global__ __launch_bounds__(256) void v1t_kernel(const float* __restrict__ vwr,
                                                  const float* __restrict__ vwi,
                                                  float2* __restrict__ vwT){
  int t = blockIdx.x*256 + threadIdx.x;   // 65536 = (i*256+c)*64 + m
  int m = t & 63, r = t >> 6, i = r >> 8, c = r & 255;
  vwT[((size_t)m*256 + c)*4 + i] = f2(vwr[t], vwi[t]);
}

// ---------------------------------------------------------------------------
// K4: fused vconv + attention-apply. Block per (b,hh,m-pair). Uf[n][m][c].
// Weights from vwT (coalesced contiguous slab).
// ---------------------------------------------------------------------------
__global__ __launch_bounds__(256) void uspec_kernel(const float2* __restrict__ Vf,
                                                    const float2* __restrict__ vwT,
                                                    const float* __restrict__ A,
                                                    float2* __restrict__ Uf){
  int bid = blockIdx.x;                // b*256 + hh*32 + mg
  int mg = bid & 31, hh = (bid >> 5) & 7, b = bid >> 8;
  int m0 = mg*2;
  int nbase = b*32 + hh*4;
  int tid = threadIdx.x;
  __shared__ float2 s_vw[4][2][256];   // [i][mm][c]
  __shared__ float2 s_vv[4][2][256];   // [smp][mm][c]
  __shared__ float  s_A[32][33];
  __shared__ float2 s_vf[4][4][2];
  for (int k = tid; k < 2048; k += 256){
    int mm = k >> 10, c = (k >> 2) & 255, i = k & 3;
    s_vw[i][mm][c] = vwT[(size_t)m0*1024 + k];
  }
  for (int k = tid; k < 1024; k += 256)
    s_A[k>>5][k&31] = A[(size_t)((b*8+hh)*32 + (k>>5))*32 + (k&31)];
  if (tid < 32){
    int smp = tid >> 3, i = (tid >> 1) & 3, mm = tid & 1;
    s_vf[smp][i][mm] = Vf[((size_t)(nbase+smp)*4 + i)*64 + m0 + mm];
  }
  __syncthreads();
  for (int k = tid; k < 2048; k += 256){
    int smp = k >> 9, mm = (k >> 8) & 1, c = k & 255;
    float sr = 0.f, si = 0.f;
    for (int i = 0; i < 4; ++i){
      float2 v = s_vf[smp][i][mm];
      float2 w = s_vw[i][mm][c];
      sr += v.x*w.x - v.y*w.y;
      si += v.x*w.y + v.y*w.x;
    }
    s_vv[smp][mm][c] = f2(sr, si);
  }
  __syncthreads();
  int sg = tid >> 5, d = tid & 31;
  float2 acc[4][2];
  for (int ss = 0; ss < 4; ++ss)
    for (int mm = 0; mm < 2; ++mm) acc[ss][mm] = f2(0.f, 0.f);
  for (int tt = 0; tt < 32; ++tt){
    int tg = tt >> 3, c = (tt & 7)*32 + d;
    float a0 = s_A[sg*4+0][tt], a1 = s_A[sg*4+1][tt];
    float a2 = s_A[sg*4+2][tt], a3 = s_A[sg*4+3][tt];
    for (int mm = 0; mm < 2; ++mm){
      float2 v = s_vv[tg][mm][c];
      acc[0][mm].x += a0*v.x; acc[0][mm].y += a0*v.y;
      acc[1][mm].x += a1*v.x; acc[1][mm].y += a1*v.y;
      acc[2][mm].x += a2*v.x; acc[2][mm].y += a2*v.y;
      acc[3][mm].x += a3*v.x; acc[3][mm].y += a3*v.y;
    }
  }
  for (int ss = 0; ss < 4; ++ss){
    int n = b*32 + sg*4 + ss;
    for (int mm = 0; mm < 2; ++mm)
      Uf[((size_t)n*64 + m0 + mm)*256 + hh*32 + d] = acc[ss][mm];
  }
}

// ---------------------------------------------------------------------------
// K4b: u1w -> u1wT[m][c][o1] float4 {pr*wr, pi*wi, pr*wi, pi*wr}.
// Coalesced reads, 16B scattered writes.
// ---------------------------------------------------------------------------
__global__ __launch_bounds__(256) void u1t_kernel(const float* __restrict__ u1wr,
                                                  const float* __restrict__ u1wi,
                                                  float4* __restrict__ u1wT){
  int t = blockIdx.x*256 + threadIdx.x;   // 524288 = (c*32+o1)*64 + m
  int m = t & 63, r = t >> 6, c = r >> 5, o1 = r & 31;
  float pr = ((m & 7)==0 && m) ? 0.5f : 1.0f;
  float pi = m ? pr : 0.0f;
  float wr = u1wr[t], wi = u1wi[t];
  u1wT[((size_t)m*256 + c)*32 + o1] = make_float4(pr*wr, pi*wi, pr*wi, pi*wr);
}

// ---------------------------------------------------------------------------
// K5: channel mixes, 4 samples/block. U1f = P(Uf) x u1w, S1f = Uf x s1w.
// Grid 256 = 16 ngroup x 16 mg. 128 threads = (o1, mm).
// ---------------------------------------------------------------------------
__global__ __launch_bounds__(128) void mix1_kernel(const float2* __restrict__ Uf,
                                                   const float4* __restrict__ u1wT,
                                                   const float* __restrict__ s1w,
                                                   float2* __restrict__ U1f, float2* __restrict__ S1f){
  int bid = blockIdx.x;
  int n0 = (bid >> 4)*4, mg = bid & 15, m0 = mg*4;
  int tid = threadIdx.x;
  __shared__ float2 s_u[4][4][256];    // [smp][mm][c]
  for (int k = tid; k < 4096; k += 128){
    int smp = k >> 10, mm = (k >> 8) & 3, c = k & 255;
    s_u[smp][mm][c] = Uf[((size_t)(n0+smp)*64 + m0 + mm)*256 + c];
  }
  __syncthreads();
  int o1 = tid & 31, mm = tid >> 5;
  int m = m0 + mm;
  const float4* wp = u1wT + (size_t)m*8192 + o1;
  const float* swp = s1w + o1*256;
  float2 au[4], asv[4];
  #pragma unroll
  for (int s = 0; s < 4; ++s){ au[s] = f2(0.f,0.f); asv[s] = f2(0.f,0.f); }
  for (int c = 0; c < 256; ++c){
    float4 w = wp[(size_t)c*32];
    float sw = swp[c];
    #pragma unroll
    for (int s = 0; s < 4; ++s){
      float2 u = s_u[s][mm][c];
      au[s].x  += u.x*w.x - u.y*w.y;
      au[s].y  += u.x*w.z + u.y*w.w;
      asv[s].x += u.x*sw;
      asv[s].y += u.y*sw;
    }
  }
  #pragma unroll
  for (int s = 0; s < 4; ++s){
    size_t ob = ((size_t)(n0+s)*32 + o1)*64 + m;
    U1f[ob] = au[s]; S1f[ob] = asv[s];
  }
}

// ---------------------------------------------------------------------------
// K6: Xg = DFT8x8( gelu( irfft(U1f) ) ), 2 fields per block, all in LDS.
// ---------------------------------------------------------------------------
__global__ __launch_bounds__(256) void xg_kernel(const float2* __restrict__ Etab,
                                                 const float2* __restrict__ U1f,
                                                 float2* __restrict__ Xg){
  int f0 = blockIdx.x*2, tid = threadIdx.x;
  __shared__ float2 s_e[64][8];
  __shared__ float2 s_gu[2][64];
  __shared__ float2 s_tu[2][64][8];    // re-used as s_a1 after phase B
  __shared__ float  s_fld[2][64*68];
  for (int e = tid; e < 512; e += 256) ((float2*)s_e)[e] = Etab[e];
  if (tid < 128) ((float2*)s_gu)[tid] = U1f[(size_t)f0*NM + tid];
  __syncthreads();
  // phase A: y-transforms for both fields (1024 items)
  for (int o = tid; o < 1024; o += 256){
    int fl = o >> 9, r = o & 511, y = r >> 3, kx = r & 7;
    float wf = (kx ? 2.0f : 1.0f) * (1.0f/4096.0f);
    float ar=0.f, ai=0.f;
    for (int ky = 0; ky < 8; ++ky){
      float2 cs = s_e[y][ky];
      float2 gu = s_gu[fl][ky*8+kx];
      ar += gu.x*cs.x - gu.y*cs.y;
      ai += gu.x*cs.y + gu.y*cs.x;
    }
    s_tu[fl][y][kx] = f2(ar*wf, ai*wf);
  }
  __syncthreads();
  // phase B: pixels + gelu for both fields (2x ILP)
  int xx = tid & 63;
  float2 ce[8];
  #pragma unroll
  for (int k = 0; k < 8; ++k) ce[k] = s_e[xx][k];
  #pragma unroll 2
  for (int i = 0; i < 16; ++i){
    int p = i*256 + tid, y = p >> 6;   // y wave-uniform
    const float4* tp0 = (const float4*)&s_tu[0][y][0];
    const float4* tp1 = (const float4*)&s_tu[1][y][0];
    float4 a0=tp0[0], a1=tp0[1], a2=tp0[2], a3=tp0[3];
    float4 b0=tp1[0], b1=tp1[1], b2=tp1[2], b3=tp1[3];
    float v0 = a0.x*ce[0].x - a0.y*ce[0].y + a0.z*ce[1].x - a0.w*ce[1].y
             + a1.x*ce[2].x - a1.y*ce[2].y + a1.z*ce[3].x - a1.w*ce[3].y
             + a2.x*ce[4].x - a2.y*ce[4].y + a2.z*ce[5].x - a2.w*ce[5].y
             + a3.x*ce[6].x - a3.y*ce[6].y + a3.z*ce[7].x - a3.w*ce[7].y;
    float v1 = b0.x*ce[0].x - b0.y*ce[0].y + b0.z*ce[1].x - b0.w*ce[1].y
             + b1.x*ce[2].x - b1.y*ce[2].y + b1.z*ce[3].x - b1.w*ce[3].y
             + b2.x*ce[4].x - b2.y*ce[4].y + b2.z*ce[5].x - b2.w*ce[5].y
             + b3.x*ce[6].x - b3.y*ce[6].y + b3.z*ce[7].x - b3.w*ce[7].y;
    float g0 = 0.5f * v0 * (1.0f + erff(v0 * 0.70710678f));
    float g1 = 0.5f * v1 * (1.0f + erff(v1 * 0.70710678f));
    s_fld[0][y*68 + xx] = g0;
    s_fld[1][y*68 + xx] = g1;
  }
  __syncthreads();
  // phase C: x-DFT stage 1 (writes alias s_tu — no longer read)
  float2 (*s_a1)[64][8] = s_tu;
  for (int o = tid; o < 1024; o += 256){
    int fl = o >> 9, r = o & 511, y = r >> 3, kx = r & 7;
    const float4* row = (const float4*)&s_fld[fl][y*68];
    float sr = 0.f, si = 0.f;
    for (int x4 = 0; x4 < 16; ++x4){
      float4 v = row[x4];
      int xb = x4*4;
      float2 c0 = s_e[xb+0][kx], c1 = s_e[xb+1][kx];
      float2 c2 = s_e[xb+2][kx], c3 = s_e[xb+3][kx];
      sr += v.x*c0.x + v.y*c1.x + v.z*c2.x + v.w*c3.x;
      si -= v.x*c0.y + v.y*c1.y + v.z*c2.y + v.w*c3.y;
    }
    s_a1[fl][y][kx] = f2(sr, si);
  }
  __syncthreads();
  // phase D: y-DFT stage 2, both fields (128 threads)
  if (tid < 128){
    int fl = tid >> 6, t6 = tid & 63;
    int ky = t6 >> 3, kx = t6 & 7;
    float sr = 0.f, si = 0.f;
    for (int y = 0; y < 64; ++y){
      float2 a = s_a1[fl][y][kx];
      float2 cs = s_e[y][ky];
      sr += a.x*cs.x + a.y*cs.y;
      si += a.y*cs.x - a.x*cs.y;
    }
    Xg[(size_t)(f0+fl)*NM + t6] = f2(sr, si);
  }
}

// ---------------------------------------------------------------------------
// K7: fused final. X1f = Xg + P(S1f) + 4096*s1b*dc; X2f = X1f x u2w;
// out = irfft(X2f + s2xS1f) + s2 x gelu(irfft(U1f)) [recomputed] + const.
// ---------------------------------------------------------------------------
__global__ __launch_bounds__(256) void final_kernel(const float2* __restrict__ Etab,
                                                    const float2* __restrict__ U1f,
                                                    const float2* __restrict__ S1f,
                                                    const float2* __restrict__ Xg,
                                                    const float* __restrict__ u2wr, const float* __restrict__ u2wi,
                                                    const float* __restrict__ s1b,
                                                    const float* __restrict__ s2w, const float* __restrict__ s2b,
                                                    float* __restrict__ out){
  int n = blockIdx.x >> 4, tile = blockIdx.x & 15, y0 = tile*4;
  int tid = threadIdx.x;
  __shared__ float2 s_e[64][8];
  __shared__ float2 s_u1[32][64];
  __shared__ float2 s_T[32][4][8];
  __shared__ float2 s_os[4][64];
  __shared__ float2 s_tmp[4][4][8];
  __shared__ float  s_w2[128], s_s1b[32], s_b2[4];
  for (int e = tid; e < 512; e += 256) ((float2*)s_e)[e] = Etab[e];
  for (int k = tid; k < 2048; k += 256) ((float2*)s_u1)[k] = U1f[(size_t)n*2048 + k];
  if (tid < 128) s_w2[tid] = s2w[tid];
  else if (tid < 160) s_s1b[tid-128] = s1b[tid-128];
  else if (tid < 164) s_b2[tid-160] = s2b[tid-160];
  __syncthreads();
  for (int e = tid; e < 1024; e += 256){
    int c = e >> 5, yy = (e >> 3) & 3, kx = e & 7;
    int y = y0 + yy;
    float wf = (kx ? 2.0f : 1.0f) * (1.0f/4096.0f);
    float ar = 0.f, ai = 0.f;
    for (int ky = 0; ky < 8; ++ky){
      float2 cs = s_e[y][ky];
      float2 g = s_u1[c][ky*8+kx];
      ar += g.x*cs.x - g.y*cs.y;
      ai += g.x*cs.y + g.y*cs.x;
    }
    s_T[c][yy][kx] = f2(ar*wf, ai*wf);
  }
  {
    int o2 = tid >> 6, m = tid & 63;
    float prm = ((m & 7)==0 && m) ? 0.5f : 1.0f;
    float pim = m ? prm : 0.0f;
    float dc = (m == 0) ? 4096.0f : 0.0f;
    float cr = 0.f, ci = 0.f;
    for (int o1 = 0; o1 < 32; ++o1){
      float2 xg = Xg[((size_t)n*32 + o1)*NM + m];
      float2 sf = S1f[((size_t)n*32 + o1)*NM + m];
      float Xr = xg.x + sf.x*prm + dc*s_s1b[o1];
      float Xi = xg.y + sf.y*pim;
      size_t wb = ((size_t)(o1*IN_CH + o2))*NM + m;
      float wr = u2wr[wb], wi = u2wi[wb];
      float sw = s_w2[o2*32 + o1];
      cr += Xr*wr - Xi*wi + sw*sf.x;
      ci += Xr*wi + Xi*wr + sw*sf.y;
    }
    s_os[o2][m] = f2(cr, ci);
  }
  __syncthreads();
  if (tid < 128){
    int o2 = tid >> 5, yy = (tid >> 3) & 3, kx = tid & 7;
    int y = y0 + yy;
    float wf = (kx ? 2.0f : 1.0f) * (1.0f/4096.0f);
    float tr=0.f, ti=0.f;
    for (int ky = 0; ky < 8; ++ky){
      float2 cs = s_e[y][ky];
      float2 g = s_os[o2][ky*8+kx];
      tr += g.x*cs.x - g.y*cs.y;
      ti += g.x*cs.y + g.y*cs.x;
    }
    s_tmp[o2][yy][kx] = f2(tr*wf, ti*wf);
  }
  __syncthreads();
  int yy = tid >> 6, xx = tid & 63;
  float2 ce[8];
  #pragma unroll
  for (int k = 0; k < 8; ++k) ce[k] = s_e[xx][k];
  float a0 = s_b2[0], a1 = s_b2[1], a2 = s_b2[2], a3 = s_b2[3];
  for (int c = 0; c < 32; ++c){
    float b = s_s1b[c];
    a0 += s_w2[c]*b; a1 += s_w2[32+c]*b; a2 += s_w2[64+c]*b; a3 += s_w2[96+c]*b;
  }
  for (int c = 0; c < 32; ++c){
    const float4* tp = (const float4*)&s_T[c][yy][0];
    float4 t0 = tp[0], t1 = tp[1], t2 = tp[2], t3 = tp[3];
    float vu = t0.x*ce[0].x - t0.y*ce[0].y + t0.z*ce[1].x - t0.w*ce[1].y
             + t1.x*ce[2].x - t1.y*ce[2].y + t1.z*ce[3].x - t1.w*ce[3].y
             + t2.x*ce[4].x - t2.y*ce[4].y + t2.z*ce[5].x - t2.w*ce[5].y
             + t3.x*ce[6].x - t3.y*ce[6].y + t3.z*ce[7].x - t3.w*ce[7].y;
    float g = 0.5f * vu * (1.0f + erff(vu * 0.70710678f));
    a0 += s_w2[c]*g; a1 += s_w2[32+c]*g; a2 += s_w2[64+c]*g; a3 += s_w2[96+c]*g;
  }
  float sp[4];
  #pragma unroll
  for (int o2 = 0; o2 < 4; ++o2){
    const float4* tp = (const float4*)&s_tmp[o2][yy][0];
    float4 t0 = tp[0], t1 = tp[1], t2 = tp[2], t3 = tp[3];
    sp[o2] = t0.x*ce[0].x - t0.y*ce[0].y + t0.z*ce[1].x - t0.w*ce[1].y
           + t1.x*ce[2].x - t1.y*ce[2].y + t1.z*ce[3].x - t1.w*ce[3].y
           + t2.x*ce[4].x - t2.y*ce[4].y + t2.z*ce[5].x - t2.w*ce[5].y
           + t3.x*ce[6].x - t3.y*ce[6].y + t3.z*ce[7].x - t3.w*ce[7].y;
  }
  int p = (y0 + yy)*64 + xx;
  float* ob = out + (size_t)n*IN_CH*NPIX;
  ob[p]          = a0 + sp[0];
  ob[NPIX + p]   = a1 + sp[1];
  ob[2*NPIX + p] = a2 + sp[2];
  ob[3*NPIX + p] = a3 + sp[3];
}

extern "C" void kernel_launch(void* const* d_in, const int* in_sizes, int n_in,
                              void* d_out, int out_size, void* d_ws, size_t ws_size,
                              hipStream_t stream) {
  (void)in_sizes; (void)n_in; (void)out_size; (void)ws_size;
  const float* v    = (const float*)d_in[0];
  const float* qwr  = (const float*)d_in[1];
  const float* qwi  = (const float*)d_in[2];
  const float* kwr  = (const float*)d_in[3];
  const float* kwi  = (const float*)d_in[4];
  const float* vwr  = (const float*)d_in[5];
  const float* vwi  = (const float*)d_in[6];
  const float* u1wr = (const float*)d_in[7];
  const float* u1wi = (const float*)d_in[8];
  const float* u2wr = (const float*)d_in[9];
  const float* u2wi = (const float*)d_in[10];
  const float* s1w  = (const float*)d_in[11];
  const float* s1b  = (const float*)d_in[12];
  const float* s2w  = (const float*)d_in[13];
  const float* s2b  = (const float*)d_in[14];
  float* out = (float*)d_out;

  float* ws = (float*)d_ws;
  size_t off = 0;
  float2* Etab =(float2*)(ws + off); off += 1024;
  float2* Vf   = (float2*)(ws + off); off += (size_t)NS*IN_CH*NM*2;     // 32768
  float2* G2   = (float2*)(ws + off); off += (size_t)65536*2;           // 131072
  float*  Gdc  =          (ws + off); off += 4096;
  float*  A    =          (ws + off); off += 16384;
  float2* Uf   = (float2*)(ws + off); off += (size_t)NS*NM*HD*2;        // 2097152
  float2* U1f  = (float2*)(ws + off); off += (size_t)NS*HIDC*NM*2;      // 262144
  float2* S1f  = (float2*)(ws + off); off += (size_t)NS*HIDC*NM*2;      // 262144
  float2* Xg   = (float2*)(ws + off); off += (size_t)NS*HIDC*NM*2;      // 262144
  float4* u1wT = (float4*)(ws + off); off += (size_t)524288*4;          // 2097152
  float2* vwT  = (float2*)(ws + off); off += (size_t)65536*2;           // 131072

  twiddle_kernel<<<1, 512, 0, stream>>>(Etab);
  fwd_dft_kernel<<<NS*IN_CH, 512, 0, stream>>>(v, Etab, Vf);
  gram_kernel<<<64, 256, 0, stream>>>(qwr, qwi, kwr, kwi, G2, Gdc);
  u1t_kernel<<<2048, 256, 0, stream>>>(u1wr, u1wi, u1wT);
  v1t_kernel<<<256, 256, 0, stream>>>(vwr, vwi, vwT);
  attn_kernel<<<512, 256, 0, stream>>>(Vf, G2, Gdc, A);
  uspec_kernel<<<512, 256, 0, stream>>>(Vf, vwT, A, Uf);
  mix1_kernel<<<256, 128, 0, stream>>>(Uf, u1wT, s1w, U1f, S1f);
  xg_kernel<<<1024, 256, 0, stream>>>(Etab, U1f, Xg);
  final_kernel<<<NS*16, 256, 0, stream>>>(Etab, U1f, S1f, Xg, u2wr, u2wi, s1b, s2w, s2b, out);
}

// Round 8
// 233.153 us; speedup vs baseline: 1.0311x; 1.0311x over previous
//
#include <hip/hip_runtime.h>
#include <math.h>

#define HEADS 8
#define HIDC  32
#define MODES 8
#define IN_CH 4
#define SEQ   32
#define NS    64      // B*SEQ samples
#define HD    256     // HEADS*HIDC
#define NM    64      // MODES*MODES
#define NPIX  4096    // 64*64
#define TWO_PI_D 6.283185307179586476925286766559

__device__ __forceinline__ float2 f2(float a, float b){ return make_float2(a,b); }

// ---------------------------------------------------------------------------
// K0: twiddle table Etab[a][b] = (cos,sin)(2*pi*((a*b)&63)/64). Built once.
// ---------------------------------------------------------------------------
__global__ void twiddle_kernel(float2* __restrict__ Etab){
  int t = threadIdx.x;                // 512 threads
  int a = t >> 3, b = t & 7;
  double sv, cv; sincos(TWO_PI_D * ((a*b) & 63) / 64.0, &sv, &cv);
  Etab[t] = f2((float)cv, (float)sv);
}

// ---------------------------------------------------------------------------
// K1: partial forward DFT of v: per field [64][64] -> 8x8 low modes.
// ---------------------------------------------------------------------------
__global__ __launch_bounds__(512) void fwd_dft_kernel(const float* __restrict__ src,
                                                      const float2* __restrict__ Etab,
                                                      float2* __restrict__ dst){
  int f = blockIdx.x, tid = threadIdx.x;
  __shared__ float  s_fld[64*68];
  __shared__ float2 s_e[64][8];
  __shared__ float2 s_a1[64][8];
  if (tid < 512) ((float2*)s_e)[tid] = Etab[tid];
  const float4* f4 = (const float4*)(src + (size_t)f*NPIX);
  for (int k = tid; k < 1024; k += 512){
    float4 v = f4[k];
    int y = k >> 4, x4 = (k & 15)*4;
    float* row = &s_fld[y*68 + x4];
    row[0]=v.x; row[1]=v.y; row[2]=v.z; row[3]=v.w;
  }
  __syncthreads();
  {
    int y = tid >> 3, kx = tid & 7;
    const float4* row = (const float4*)&s_fld[y*68];
    float sr0=0.f, si0=0.f, sr1=0.f, si1=0.f;
    for (int x4 = 0; x4 < 8; ++x4){
      float4 v = row[x4];
      int xb = x4*4;
      float2 c0 = s_e[xb+0][kx], c1 = s_e[xb+1][kx];
      float2 c2 = s_e[xb+2][kx], c3 = s_e[xb+3][kx];
      sr0 += v.x*c0.x + v.y*c1.x + v.z*c2.x + v.w*c3.x;
      si0 -= v.x*c0.y + v.y*c1.y + v.z*c2.y + v.w*c3.y;
    }
    for (int x4 = 8; x4 < 16; ++x4){
      float4 v = row[x4];
      int xb = x4*4;
      float2 c0 = s_e[xb+0][kx], c1 = s_e[xb+1][kx];
      float2 c2 = s_e[xb+2][kx], c3 = s_e[xb+3][kx];
      sr1 += v.x*c0.x + v.y*c1.x + v.z*c2.x + v.w*c3.x;
      si1 -= v.x*c0.y + v.y*c1.y + v.z*c2.y + v.w*c3.y;
    }
    s_a1[y][kx] = f2(sr0+sr1, si0+si1);
  }
  __syncthreads();
  if (tid < 64){
    int ky = tid >> 3, kx = tid & 7;
    float sr0=0.f, si0=0.f, sr1=0.f, si1=0.f;
    for (int y = 0; y < 32; ++y){
      float2 a = s_a1[y][kx];
      float2 cs = s_e[y][ky];
      sr0 += a.x*cs.x + a.y*cs.y;
      si0 += a.y*cs.x - a.x*cs.y;
    }
    for (int y = 32; y < 64; ++y){
      float2 a = s_a1[y][kx];
      float2 cs = s_e[y][ky];
      sr1 += a.x*cs.x + a.y*cs.y;
      si1 += a.y*cs.x - a.x*cs.y;
    }
    dst[(size_t)f*NM + tid] = f2(sr0+sr1, si0+si1);
  }
}

// ---------------------------------------------------------------------------
// K2: weight Grams, block per mode m; G2 pre-scaled by Parseval weight.
// ---------------------------------------------------------------------------
__global__ __launch_bounds__(256) void gram_kernel(const float* __restrict__ qwr, const float* __restrict__ qwi,
                                                   const float* __restrict__ kwr, const float* __restrict__ kwi,
                                                   float2* __restrict__ G2, float* __restrict__ Gdc){
  int m = blockIdx.x, tid = threadIdx.x;
  __shared__ float qsr[4][257], qsi[4][257], ksr[4][257], ksi[4][257];
  for (int k = tid; k < 1024; k += 256){
    int i = k >> 8, c = k & 255;
    size_t a = ((size_t)(i*256 + c))*64 + m;
    qsr[i][c] = qwr[a]; qsi[i][c] = qwi[a];
    ksr[i][c] = kwr[a]; ksi[i][c] = kwi[a];
  }
  __syncthreads();
  int kx = m & 7, ky = m >> 3;
  float w = (kx >= 1) ? 2.0f : ((ky >= 1) ? 0.5f : 0.0f);
  for (int e = tid; e < 1024; e += 256){
    int P = e >> 7, T = (e >> 4) & 7, i = (e >> 2) & 3, j = e & 3;
    float grr=0.f, gri=0.f, gir=0.f, gii=0.f;
    for (int d = 0; d < 32; ++d){
      float ar = qsr[i][P*32+d], ai = qsi[i][P*32+d];
      float br = ksr[j][T*32+d], bi = ksi[j][T*32+d];
      grr += ar*br; gri += ar*bi; gir += ai*br; gii += ai*bi;
    }
    G2[(size_t)(((m*8+P)*4+i)*4+j)*8 + T] = f2(w*(grr+gii), w*(gir-gri));
    if (m == 0){
      int o = ((P*4+i)*4+j)*8 + T;
      Gdc[o] = grr; Gdc[1024+o] = gri; Gdc[2048+o] = gir; Gdc[3072+o] = gii;
    }
  }
}

// ---------------------------------------------------------------------------
// K3: attention logits via Parseval + softmax -> A.
// ---------------------------------------------------------------------------
__global__ __launch_bounds__(256) void attn_kernel(const float2* __restrict__ Vf,
                                                   const float2* __restrict__ G2,
                                                   const float* __restrict__ Gdc,
                                                   float* __restrict__ A){
  int bx = blockIdx.x;                 // (b<<8)|(hh<<5)|s
  int s = bx & 31;
  int base = ((bx >> 8) * 32) + (((bx >> 5) & 7) * 4);
  int tid = threadIdx.x;
  int t = tid & 31, mc = tid >> 5;
  __shared__ float2 s_vf[4][IN_CH][64];
  __shared__ float  s_part[8][33];
  for (int k = tid; k < 4*IN_CH*64; k += 256){
    int m = k & 63, c = (k>>6)&3, smp = k>>8;
    s_vf[smp][c][m] = Vf[((size_t)(base+smp)*IN_CH + c)*NM + m];
  }
  __syncthreads();
  int sg = s >> 3, P = s & 7;
  int tg = t >> 3, T = t & 7;
  float acc = 0.f;
  for (int mm = 0; mm < 8; ++mm){
    int m = mc*8 + mm;
    const float2* g = G2 + (size_t)((m*8+P)*16)*8 + T;
    float sub = 0.f;
    for (int i = 0; i < 4; ++i){
      float2 a = s_vf[sg][i][m];
      for (int j = 0; j < 4; ++j){
        float2 b = s_vf[tg][j][m];
        float zr = a.x*b.x + a.y*b.y;
        float zi = a.y*b.x - a.x*b.y;
        float2 gv = g[(size_t)(i*4+j)*8];
        sub += zr*gv.x - zi*gv.y;
      }
    }
    acc += sub;
  }
  if (mc == 0){
    float sub = 0.f;
    for (int i = 0; i < 4; ++i){
      float2 a = s_vf[sg][i][0];
      for (int j = 0; j < 4; ++j){
        float2 b = s_vf[tg][j][0];
        int o = ((P*4+i)*4+j)*8 + T;
        sub += a.x*b.x*Gdc[o] - a.x*b.y*Gdc[1024+o]
             - a.y*b.x*Gdc[2048+o] + a.y*b.y*Gdc[3072+o];
      }
    }
    acc += sub;
  }
  s_part[mc][t] = acc;
  __syncthreads();
  if (tid < 32){
    float l2 = 0.f;
    for (int k = 0; k < 8; ++k) l2 += s_part[k][tid];
    l2 *= 0.5f / (4096.0f * 4096.0f);
    float mx = l2;
    for (int off = 16; off; off >>= 1) mx = fmaxf(mx, __shfl_xor(mx, off, 32));
    float e = expf(l2 - mx);
    float sm = e;
    for (int off = 16; off; off >>= 1) sm += __shfl_xor(sm, off, 32);
    A[(size_t)bx*32 + tid] = e / sm;
  }
}

// ---------------------------------------------------------------------------
// K3b: transpose vw -> vwT[m][c][i] float2 (coalesced reads).
// ---------------------------------------------------------------------------
__global__ __launch_bounds__(256) void v1t_kernel(const float* __restrict__ vwr,
                                                  const float* __restrict__ vwi,
                                                  float2* __restrict__ vwT){
  int t = blockIdx.x*256 + threadIdx.x;   // 65536 = (i*256+c)*64 + m
  int m = t & 63, r = t >> 6, i = r >> 8, c = r & 255;
  vwT[((size_t)m*256 + c)*4 + i] = f2(vwr[t], vwi[t]);
}

// ---------------------------------------------------------------------------
// K4: fused vconv + attention-apply. Block per (b,hh,m-pair). Uf[n][m][c].
// ---------------------------------------------------------------------------
__global__ __launch_bounds__(256) void uspec_kernel(const float2* __restrict__ Vf,
                                                    const float2* __restrict__ vwT,
                                                    const float* __restrict__ A,
                                                    float2* __restrict__ Uf){
  int bid = blockIdx.x;                // b*256 + hh*32 + mg
  int mg = bid & 31, hh = (bid >> 5) & 7, b = bid >> 8;
  int m0 = mg*2;
  int nbase = b*32 + hh*4;
  int tid = threadIdx.x;
  __shared__ float2 s_vw[4][2][256];   // [i][mm][c]
  __shared__ float2 s_vv[4][2][256];   // [smp][mm][c]
  __shared__ float  s_A[32][33];
  __shared__ float2 s_vf[4][4][2];
  for (int k = tid; k < 2048; k += 256){
    int mm = k >> 10, c = (k >> 2) & 255, i = k & 3;
    s_vw[i][mm][c] = vwT[(size_t)m0*1024 + k];
  }
  for (int k = tid; k < 1024; k += 256)
    s_A[k>>5][k&31] = A[(size_t)((b*8+hh)*32 + (k>>5))*32 + (k&31)];
  if (tid < 32){
    int smp = tid >> 3, i = (tid >> 1) & 3, mm = tid & 1;
    s_vf[smp][i][mm] = Vf[((size_t)(nbase+smp)*4 + i)*64 + m0 + mm];
  }
  __syncthreads();
  for (int k = tid; k < 2048; k += 256){
    int smp = k >> 9, mm = (k >> 8) & 1, c = k & 255;
    float sr = 0.f, si = 0.f;
    for (int i = 0; i < 4; ++i){
      float2 v = s_vf[smp][i][mm];
      float2 w = s_vw[i][mm][c];
      sr += v.x*w.x - v.y*w.y;
      si += v.x*w.y + v.y*w.x;
    }
    s_vv[smp][mm][c] = f2(sr, si);
  }
  __syncthreads();
  int sg = tid >> 5, d = tid & 31;
  float2 acc[4][2];
  for (int ss = 0; ss < 4; ++ss)
    for (int mm = 0; mm < 2; ++mm) acc[ss][mm] = f2(0.f, 0.f);
  for (int tt = 0; tt < 32; ++tt){
    int tg = tt >> 3, c = (tt & 7)*32 + d;
    float a0 = s_A[sg*4+0][tt], a1 = s_A[sg*4+1][tt];
    float a2 = s_A[sg*4+2][tt], a3 = s_A[sg*4+3][tt];
    for (int mm = 0; mm < 2; ++mm){
      float2 v = s_vv[tg][mm][c];
      acc[0][mm].x += a0*v.x; acc[0][mm].y += a0*v.y;
      acc[1][mm].x += a1*v.x; acc[1][mm].y += a1*v.y;
      acc[2][mm].x += a2*v.x; acc[2][mm].y += a2*v.y;
      acc[3][mm].x += a3*v.x; acc[3][mm].y += a3*v.y;
    }
  }
  for (int ss = 0; ss < 4; ++ss){
    int n = b*32 + sg*4 + ss;
    for (int mm = 0; mm < 2; ++mm)
      Uf[((size_t)n*64 + m0 + mm)*256 + hh*32 + d] = acc[ss][mm];
  }
}

// ---------------------------------------------------------------------------
// K4b: u1w -> u1wT[m][c][o1] float4 {pr*wr, pi*wi, pr*wi, pi*wr}.
// ---------------------------------------------------------------------------
__global__ __launch_bounds__(256) void u1t_kernel(const float* __restrict__ u1wr,
                                                  const float* __restrict__ u1wi,
                                                  float4* __restrict__ u1wT){
  int t = blockIdx.x*256 + threadIdx.x;   // 524288 = (c*32+o1)*64 + m
  int m = t & 63, r = t >> 6, c = r >> 5, o1 = r & 31;
  float pr = ((m & 7)==0 && m) ? 0.5f : 1.0f;
  float pi = m ? pr : 0.0f;
  float wr = u1wr[t], wi = u1wi[t];
  u1wT[((size_t)m*256 + c)*32 + o1] = make_float4(pr*wr, pi*wi, pr*wi, pi*wr);
}

// ---------------------------------------------------------------------------
// K5: channel mixes. Block = (8 samples) x (2 modes); 256 thr = (o1, mm, sh);
// each thread 2 samples -> 4 independent acc chains. s1w staged (padded).
// ---------------------------------------------------------------------------
__global__ __launch_bounds__(256) void mix1_kernel(const float2* __restrict__ Uf,
                                                   const float4* __restrict__ u1wT,
                                                   const float* __restrict__ s1w,
                                                   float2* __restrict__ U1f, float2* __restrict__ S1f){
  int bid = blockIdx.x;                // 256 = ng(8) x mg(32)
  int mg = bid & 31, n0 = (bid >> 5)*8, m0 = mg*2;
  int tid = threadIdx.x;
  __shared__ float2 s_u[8][2][256];    // [s][mm][c] : 32 KB
  __shared__ float  s_w1[32][257];     // padded: o1-major, conflict-free
  for (int it = 0; it < 16; ++it){
    int s = it >> 1, mm = it & 1;
    s_u[s][mm][tid] = Uf[((size_t)(n0+s)*64 + m0 + mm)*256 + tid];
  }
  for (int k = tid; k < 8192; k += 256)
    s_w1[k>>8][k&255] = s1w[k];
  __syncthreads();
  int o1 = tid & 31, mm = (tid >> 5) & 1, sh = tid >> 6;   // sh in 0..3
  int m = m0 + mm, sA = sh*2, sB = sh*2+1;
  const float4* wp = u1wT + (size_t)m*8192 + o1;
  float2 au0 = f2(0,0), au1 = f2(0,0), as0 = f2(0,0), as1 = f2(0,0);
  #pragma unroll 4
  for (int c = 0; c < 256; ++c){
    float4 w = wp[(size_t)c*32];
    float sw = s_w1[o1][c];
    float2 uA = s_u[sA][mm][c];
    float2 uB = s_u[sB][mm][c];
    au0.x += uA.x*w.x - uA.y*w.y;  au0.y += uA.x*w.z + uA.y*w.w;
    au1.x += uB.x*w.x - uB.y*w.y;  au1.y += uB.x*w.z + uB.y*w.w;
    as0.x += uA.x*sw;  as0.y += uA.y*sw;
    as1.x += uB.x*sw;  as1.y += uB.y*sw;
  }
  size_t obA = ((size_t)(n0+sA)*32 + o1)*64 + m;
  size_t obB = ((size_t)(n0+sB)*32 + o1)*64 + m;
  U1f[obA] = au0; S1f[obA] = as0;
  U1f[obB] = au1; S1f[obB] = as1;
}

// ---------------------------------------------------------------------------
// K6: Xg = DFT8x8( gelu( irfft(U1f) ) ), 2 fields/block, 512 threads.
// ---------------------------------------------------------------------------
__global__ __launch_bounds__(512) void xg_kernel(const float2* __restrict__ Etab,
                                                 const float2* __restrict__ U1f,
                                                 float2* __restrict__ Xg){
  int f0 = blockIdx.x*2, tid = threadIdx.x;
  __shared__ float2 s_e[64][8];
  __shared__ float2 s_eT[8][64];       // transposed copy: conflict-free ce hoist
  __shared__ float2 s_gu[2][64];
  __shared__ float2 s_tu[2][64][8];    // aliased as s_a1 after phase B
  __shared__ float  s_fld[2][64*68];
  if (tid < 512){
    float2 v = Etab[tid];
    int a = tid >> 3, b = tid & 7;
    s_e[a][b] = v; s_eT[b][a] = v;
  }
  if (tid < 128) ((float2*)s_gu)[tid] = U1f[(size_t)f0*NM + tid];
  __syncthreads();
  // phase A: y-transforms, 1024 items, 2/thread, split partials
  for (int o = tid; o < 1024; o += 512){
    int fl = o >> 9, r = o & 511, y = r >> 3, kx = r & 7;
    float wf = (kx ? 2.0f : 1.0f) * (1.0f/4096.0f);
    float a0=0.f, b0=0.f, a1=0.f, b1=0.f;
    for (int ky = 0; ky < 4; ++ky){
      float2 cs = s_e[y][ky];
      float2 gu = s_gu[fl][ky*8+kx];
      a0 += gu.x*cs.x - gu.y*cs.y;
      b0 += gu.x*cs.y + gu.y*cs.x;
    }
    for (int ky = 4; ky < 8; ++ky){
      float2 cs = s_e[y][ky];
      float2 gu = s_gu[fl][ky*8+kx];
      a1 += gu.x*cs.x - gu.y*cs.y;
      b1 += gu.x*cs.y + gu.y*cs.x;
    }
    s_tu[fl][y][kx] = f2((a0+a1)*wf, (b0+b1)*wf);
  }
  __syncthreads();
  // phase B: pixels + gelu, both fields, 8 px each per field
  int xx = tid & 63;
  float2 ce[8];
  #pragma unroll
  for (int k = 0; k < 8; ++k) ce[k] = s_eT[k][xx];
  for (int i = 0; i < 8; ++i){
    int p = i*512 + tid, y = p >> 6;   // wave-uniform y
    const float4* tp0 = (const float4*)&s_tu[0][y][0];
    const float4* tp1 = (const float4*)&s_tu[1][y][0];
    float4 a0=tp0[0], a1=tp0[1], a2=tp0[2], a3=tp0[3];
    float4 b0=tp1[0], b1=tp1[1], b2=tp1[2], b3=tp1[3];
    float h0 = a0.x*ce[0].x - a0.y*ce[0].y + a0.z*ce[1].x - a0.w*ce[1].y
             + a1.x*ce[2].x - a1.y*ce[2].y + a1.z*ce[3].x - a1.w*ce[3].y;
    float h1 = a2.x*ce[4].x - a2.y*ce[4].y + a2.z*ce[5].x - a2.w*ce[5].y
             + a3.x*ce[6].x - a3.y*ce[6].y + a3.z*ce[7].x - a3.w*ce[7].y;
    float g0 = a0.x*0.f;  // keep var count low; (dummy removed by compiler)
    float k0 = b0.x*ce[0].x - b0.y*ce[0].y + b0.z*ce[1].x - b0.w*ce[1].y
             + b1.x*ce[2].x - b1.y*ce[2].y + b1.z*ce[3].x - b1.w*ce[3].y;
    float k1 = b2.x*ce[4].x - b2.y*ce[4].y + b2.z*ce[5].x - b2.w*ce[5].y
             + b3.x*ce[6].x - b3.y*ce[6].y + b3.z*ce[7].x - b3.w*ce[7].y;
    float v0 = h0 + h1, v1 = k0 + k1;
    float ga = 0.5f * v0 * (1.0f + erff(v0 * 0.70710678f));
    float gb = 0.5f * v1 * (1.0f + erff(v1 * 0.70710678f));
    (void)g0;
    s_fld[0][y*68 + xx] = ga;
    s_fld[1][y*68 + xx] = gb;
  }
  __syncthreads();
  // phase C: x-DFT stage 1 (writes alias s_tu)
  float2 (*s_a1)[64][8] = s_tu;
  for (int o = tid; o < 1024; o += 512){
    int fl = o >> 9, r = o & 511, y = r >> 3, kx = r & 7;
    const float4* row = (const float4*)&s_fld[fl][y*68];
    float sr0=0.f, si0=0.f, sr1=0.f, si1=0.f;
    for (int x4 = 0; x4 < 8; ++x4){
      float4 v = row[x4];
      int xb = x4*4;
      float2 c0 = s_e[xb+0][kx], c1 = s_e[xb+1][kx];
      float2 c2 = s_e[xb+2][kx], c3 = s_e[xb+3][kx];
      sr0 += v.x*c0.x + v.y*c1.x + v.z*c2.x + v.w*c3.x;
      si0 -= v.x*c0.y + v.y*c1.y + v.z*c2.y + v.w*c3.y;
    }
    for (int x4 = 8; x4 < 16; ++x4){
      float4 v = row[x4];
      int xb = x4*4;
      float2 c0 = s_e[xb+0][kx], c1 = s_e[xb+1][kx];
      float2 c2 = s_e[xb+2][kx], c3 = s_e[xb+3][kx];
      sr1 += v.x*c0.x + v.y*c1.x + v.z*c2.x + v.w*c3.x;
      si1 -= v.x*c0.y + v.y*c1.y + v.z*c2.y + v.w*c3.y;
    }
    s_a1[fl][y][kx] = f2(sr0+sr1, si0+si1);
  }
  __syncthreads();
  // phase D: y-DFT stage 2
  if (tid < 128){
    int fl = tid >> 6, t6 = tid & 63;
    int ky = t6 >> 3, kx = t6 & 7;
    float sr0=0.f, si0=0.f, sr1=0.f, si1=0.f;
    for (int y = 0; y < 32; ++y){
      float2 a = s_a1[fl][y][kx];
      float2 cs = s_e[y][ky];
      sr0 += a.x*cs.x + a.y*cs.y;
      si0 += a.y*cs.x - a.x*cs.y;
    }
    for (int y = 32; y < 64; ++y){
      float2 a = s_a1[fl][y][kx];
      float2 cs = s_e[y][ky];
      sr1 += a.x*cs.x + a.y*cs.y;
      si1 += a.y*cs.x - a.x*cs.y;
    }
    Xg[(size_t)(f0+fl)*NM + t6] = f2(sr0+sr1, si0+si1);
  }
}

// ---------------------------------------------------------------------------
// K7: fused final. X1f = Xg + P(S1f) + 4096*s1b*dc; X2f = X1f x u2w;
// out = irfft(X2f + s2xS1f) + s2 x gelu(irfft(U1f)) [recomputed] + const.
// ---------------------------------------------------------------------------
__global__ __launch_bounds__(256) void final_kernel(const float2* __restrict__ Etab,
                                                    const float2* __restrict__ U1f,
                                                    const float2* __restrict__ S1f,
                                                    const float2* __restrict__ Xg,
                                                    const float* __restrict__ u2wr, const float* __restrict__ u2wi,
                                                    const float* __restrict__ s1b,
                                                    const float* __restrict__ s2w, const float* __restrict__ s2b,
                                                    float* __restrict__ out){
  int n = blockIdx.x >> 4, tile = blockIdx.x & 15, y0 = tile*4;
  int tid = threadIdx.x;
  __shared__ float2 s_e[64][8];
  __shared__ float2 s_eT[8][64];
  __shared__ float2 s_u1[32][64];
  __shared__ float2 s_T[32][4][8];
  __shared__ float2 s_os[4][64];
  __shared__ float2 s_tmp[4][4][8];
  __shared__ float  s_w2[128], s_s1b[32], s_b2[4];
  for (int e = tid; e < 512; e += 256){
    float2 v = Etab[e];
    s_e[e>>3][e&7] = v; s_eT[e&7][e>>3] = v;
  }
  for (int k = tid; k < 2048; k += 256) ((float2*)s_u1)[k] = U1f[(size_t)n*2048 + k];
  if (tid < 128) s_w2[tid] = s2w[tid];
  else if (tid < 160) s_s1b[tid-128] = s1b[tid-128];
  else if (tid < 164) s_b2[tid-160] = s2b[tid-160];
  __syncthreads();
  for (int e = tid; e < 1024; e += 256){
    int c = e >> 5, yy = (e >> 3) & 3, kx = e & 7;
    int y = y0 + yy;
    float wf = (kx ? 2.0f : 1.0f) * (1.0f/4096.0f);
    float ar = 0.f, ai = 0.f;
    for (int ky = 0; ky < 8; ++ky){
      float2 cs = s_e[y][ky];
      float2 g = s_u1[c][ky*8+kx];
      ar += g.x*cs.x - g.y*cs.y;
      ai += g.x*cs.y + g.y*cs.x;
    }
    s_T[c][yy][kx] = f2(ar*wf, ai*wf);
  }
  {
    int o2 = tid >> 6, m = tid & 63;
    float prm = ((m & 7)==0 && m) ? 0.5f : 1.0f;
    float pim = m ? prm : 0.0f;
    float dc = (m == 0) ? 4096.0f : 0.0f;
    float cr = 0.f, ci = 0.f;
    for (int o1 = 0; o1 < 32; ++o1){
      float2 xg = Xg[((size_t)n*32 + o1)*NM + m];
      float2 sf = S1f[((size_t)n*32 + o1)*NM + m];
      float Xr = xg.x + sf.x*prm + dc*s_s1b[o1];
      float Xi = xg.y + sf.y*pim;
      size_t wb = ((size_t)(o1*IN_CH + o2))*NM + m;
      float wr = u2wr[wb], wi = u2wi[wb];
      float sw = s_w2[o2*32 + o1];
      cr += Xr*wr - Xi*wi + sw*sf.x;
      ci += Xr*wi + Xi*wr + sw*sf.y;
    }
    s_os[o2][m] = f2(cr, ci);
  }
  __syncthreads();
  if (tid < 128){
    int o2 = tid >> 5, yy = (tid >> 3) & 3, kx = tid & 7;
    int y = y0 + yy;
    float wf = (kx ? 2.0f : 1.0f) * (1.0f/4096.0f);
    float tr=0.f, ti=0.f;
    for (int ky = 0; ky < 8; ++ky){
      float2 cs = s_e[y][ky];
      float2 g = s_os[o2][ky*8+kx];
      tr += g.x*cs.x - g.y*cs.y;
      ti += g.x*cs.y + g.y*cs.x;
    }
    s_tmp[o2][yy][kx] = f2(tr*wf, ti*wf);
  }
  __syncthreads();
  int yy = tid >> 6, xx = tid & 63;
  float2 ce[8];
  #pragma unroll
  for (int k = 0; k < 8; ++k) ce[k] = s_eT[k][xx];
  float a0 = s_b2[0], a1 = s_b2[1], a2 = s_b2[2], a3 = s_b2[3];
  for (int c = 0; c < 32; ++c){
    float b = s_s1b[c];
    a0 += s_w2[c]*b; a1 += s_w2[32+c]*b; a2 += s_w2[64+c]*b; a3 += s_w2[96+c]*b;
  }
  for (int c = 0; c < 32; ++c){
    const float4* tp = (const float4*)&s_T[c][yy][0];
    float4 t0 = tp[0], t1 = tp[1], t2 = tp[2], t3 = tp[3];
    float h0 = t0.x*ce[0].x - t0.y*ce[0].y + t0.z*ce[1].x - t0.w*ce[1].y
             + t1.x*ce[2].x - t1.y*ce[2].y + t1.z*ce[3].x - t1.w*ce[3].y;
    float h1 = t2.x*ce[4].x - t2.y*ce[4].y + t2.z*ce[5].x - t2.w*ce[5].y
             + t3.x*ce[6].x - t3.y*ce[6].y + t3.z*ce[7].x - t3.w*ce[7].y;
    float vu = h0 + h1;
    float g = 0.5f * vu * (1.0f + erff(vu * 0.70710678f));
    a0 += s_w2[c]*g; a1 += s_w2[32+c]*g; a2 += s_w2[64+c]*g; a3 += s_w2[96+c]*g;
  }
  float sp[4];
  #pragma unroll
  for (int o2 = 0; o2 < 4; ++o2){
    const float4* tp = (const float4*)&s_tmp[o2][yy][0];
    float4 t0 = tp[0], t1 = tp[1], t2 = tp[2], t3 = tp[3];
    float h0 = t0.x*ce[0].x - t0.y*ce[0].y + t0.z*ce[1].x - t0.w*ce[1].y
             + t1.x*ce[2].x - t1.y*ce[2].y + t1.z*ce[3].x - t1.w*ce[3].y;
    float h1 = t2.x*ce[4].x - t2.y*ce[4].y + t2.z*ce[5].x - t2.w*ce[5].y
             + t3.x*ce[6].x - t3.y*ce[6].y + t3.z*ce[7].x - t3.w*ce[7].y;
    sp[o2] = h0 + h1;
  }
  int p = (y0 + yy)*64 + xx;
  float* ob = out + (size_t)n*IN_CH*NPIX;
  ob[p]          = a0 + sp[0];
  ob[NPIX + p]   = a1 + sp[1];
  ob[2*NPIX + p] = a2 + sp[2];
  ob[3*NPIX + p] = a3 + sp[3];
}

extern "C" void kernel_launch(void* const* d_in, const int* in_sizes, int n_in,
                              void* d_out, int out_size, void* d_ws, size_t ws_size,
                              hipStream_t stream) {
  (void)in_sizes; (void)n_in; (void)out_size; (void)ws_size;
  const float* v    = (const float*)d_in[0];
  const float* qwr  = (const float*)d_in[1];
  const float* qwi  = (const float*)d_in[2];
  const float* kwr  = (const float*)d_in[3];
  const float* kwi  = (const float*)d_in[4];
  const float* vwr  = (const float*)d_in[5];
  const float* vwi  = (const float*)d_in[6];
  const float* u1wr = (const float*)d_in[7];
  const float* u1wi = (const float*)d_in[8];
  const float* u2wr = (const float*)d_in[9];
  const float* u2wi = (const float*)d_in[10];
  const float* s1w  = (const float*)d_in[11];
  const float* s1b  = (const float*)d_in[12];
  const float* s2w  = (const float*)d_in[13];
  const float* s2b  = (const float*)d_in[14];
  float* out = (float*)d_out;

  float* ws = (float*)d_ws;
  size_t off = 0;
  float2* Etab =(float2*)(ws + off); off += 1024;
  float2* Vf   = (float2*)(ws + off); off += (size_t)NS*IN_CH*NM*2;     // 32768
  float2* G2   = (float2*)(ws + off); off += (size_t)65536*2;           // 131072
  float*  Gdc  =          (ws + off); off += 4096;
  float*  A    =          (ws + off); off += 16384;
  float2* Uf   = (float2*)(ws + off); off += (size_t)NS*NM*HD*2;        // 2097152
  float2* U1f  = (float2*)(ws + off); off += (size_t)NS*HIDC*NM*2;      // 262144
  float2* S1f  = (float2*)(ws + off); off += (size_t)NS*HIDC*NM*2;      // 262144
  float2* Xg   = (float2*)(ws + off); off += (size_t)NS*HIDC*NM*2;      // 262144
  float4* u1wT = (float4*)(ws + off); off += (size_t)524288*4;          // 2097152
  float2* vwT  = (float2*)(ws + off); off += (size_t)65536*2;           // 131072

  twiddle_kernel<<<1, 512, 0, stream>>>(Etab);
  fwd_dft_kernel<<<NS*IN_CH, 512, 0, stream>>>(v, Etab, Vf);
  gram_kernel<<<64, 256, 0, stream>>>(qwr, qwi, kwr, kwi, G2, Gdc);
  u1t_kernel<<<2048, 256, 0, stream>>>(u1wr, u1wi, u1wT);
  v1t_kernel<<<256, 256, 0, stream>>>(vwr, vwi, vwT);
  attn_kernel<<<512, 256, 0, stream>>>(Vf, G2, Gdc, A);
  uspec_kernel<<<512, 256, 0, stream>>>(Vf, vwT, A, Uf);
  mix1_kernel<<<256, 256, 0, stream>>>(Uf, u1wT, s1w, U1f, S1f);
  xg_kernel<<<1024, 512, 0, stream>>>(Etab, U1f, Xg);
  final_kernel<<<NS*16, 256, 0, stream>>>(Etab, U1f, S1f, Xg, u2wr, u2wi, s1b, s2w, s2b, out);
}

// Round 9
// 208.456 us; speedup vs baseline: 1.1532x; 1.1185x over previous
//
#include <hip/hip_runtime.h>
#include <math.h>

#define HEADS 8
#define HIDC  32
#define MODES 8
#define IN_CH 4
#define SEQ   32
#define NS    64      // B*SEQ samples
#define HD    256     // HEADS*HIDC
#define NM    64      // MODES*MODES
#define NPIX  4096    // 64*64
#define TWO_PI_D 6.283185307179586476925286766559

__device__ __forceinline__ float2 f2(float a, float b){ return make_float2(a,b); }

// ---------------------------------------------------------------------------
// K0: twiddle table Etab[a][b] = (cos,sin)(2*pi*((a*b)&63)/64). Built once.
// ---------------------------------------------------------------------------
__global__ void twiddle_kernel(float2* __restrict__ Etab){
  int t = threadIdx.x;                // 512 threads
  int a = t >> 3, b = t & 7;
  double sv, cv; sincos(TWO_PI_D * ((a*b) & 63) / 64.0, &sv, &cv);
  Etab[t] = f2((float)cv, (float)sv);
}

// ---------------------------------------------------------------------------
// K1: partial forward DFT of v: per field [64][64] -> 8x8 low modes.
// ---------------------------------------------------------------------------
__global__ __launch_bounds__(512) void fwd_dft_kernel(const float* __restrict__ src,
                                                      const float2* __restrict__ Etab,
                                                      float2* __restrict__ dst){
  int f = blockIdx.x, tid = threadIdx.x;
  __shared__ float  s_fld[64*68];
  __shared__ float2 s_e[64][8];
  __shared__ float2 s_a1[64][8];
  if (tid < 512) ((float2*)s_e)[tid] = Etab[tid];
  const float4* f4 = (const float4*)(src + (size_t)f*NPIX);
  for (int k = tid; k < 1024; k += 512){
    float4 v = f4[k];
    int y = k >> 4, x4 = (k & 15)*4;
    float* row = &s_fld[y*68 + x4];
    row[0]=v.x; row[1]=v.y; row[2]=v.z; row[3]=v.w;
  }
  __syncthreads();
  {
    int y = tid >> 3, kx = tid & 7;
    const float4* row = (const float4*)&s_fld[y*68];
    float sr0=0.f, si0=0.f, sr1=0.f, si1=0.f;
    for (int x4 = 0; x4 < 8; ++x4){
      float4 v = row[x4];
      int xb = x4*4;
      float2 c0 = s_e[xb+0][kx], c1 = s_e[xb+1][kx];
      float2 c2 = s_e[xb+2][kx], c3 = s_e[xb+3][kx];
      sr0 += v.x*c0.x + v.y*c1.x + v.z*c2.x + v.w*c3.x;
      si0 -= v.x*c0.y + v.y*c1.y + v.z*c2.y + v.w*c3.y;
    }
    for (int x4 = 8; x4 < 16; ++x4){
      float4 v = row[x4];
      int xb = x4*4;
      float2 c0 = s_e[xb+0][kx], c1 = s_e[xb+1][kx];
      float2 c2 = s_e[xb+2][kx], c3 = s_e[xb+3][kx];
      sr1 += v.x*c0.x + v.y*c1.x + v.z*c2.x + v.w*c3.x;
      si1 -= v.x*c0.y + v.y*c1.y + v.z*c2.y + v.w*c3.y;
    }
    s_a1[y][kx] = f2(sr0+sr1, si0+si1);
  }
  __syncthreads();
  if (tid < 64){
    int ky = tid >> 3, kx = tid & 7;
    float sr0=0.f, si0=0.f, sr1=0.f, si1=0.f;
    for (int y = 0; y < 32; ++y){
      float2 a = s_a1[y][kx];
      float2 cs = s_e[y][ky];
      sr0 += a.x*cs.x + a.y*cs.y;
      si0 += a.y*cs.x - a.x*cs.y;
    }
    for (int y = 32; y < 64; ++y){
      float2 a = s_a1[y][kx];
      float2 cs = s_e[y][ky];
      sr1 += a.x*cs.x + a.y*cs.y;
      si1 += a.y*cs.x - a.x*cs.y;
    }
    dst[(size_t)f*NM + tid] = f2(sr0+sr1, si0+si1);
  }
}

// ---------------------------------------------------------------------------
// K2: weight Grams, block per mode m; G2 pre-scaled by Parseval weight.
// ---------------------------------------------------------------------------
__global__ __launch_bounds__(256) void gram_kernel(const float* __restrict__ qwr, const float* __restrict__ qwi,
                                                   const float* __restrict__ kwr, const float* __restrict__ kwi,
                                                   float2* __restrict__ G2, float* __restrict__ Gdc){
  int m = blockIdx.x, tid = threadIdx.x;
  __shared__ float qsr[4][257], qsi[4][257], ksr[4][257], ksi[4][257];
  for (int k = tid; k < 1024; k += 256){
    int i = k >> 8, c = k & 255;
    size_t a = ((size_t)(i*256 + c))*64 + m;
    qsr[i][c] = qwr[a]; qsi[i][c] = qwi[a];
    ksr[i][c] = kwr[a]; ksi[i][c] = kwi[a];
  }
  __syncthreads();
  int kx = m & 7, ky = m >> 3;
  float w = (kx >= 1) ? 2.0f : ((ky >= 1) ? 0.5f : 0.0f);
  for (int e = tid; e < 1024; e += 256){
    int P = e >> 7, T = (e >> 4) & 7, i = (e >> 2) & 3, j = e & 3;
    float grr=0.f, gri=0.f, gir=0.f, gii=0.f;
    for (int d = 0; d < 32; ++d){
      float ar = qsr[i][P*32+d], ai = qsi[i][P*32+d];
      float br = ksr[j][T*32+d], bi = ksi[j][T*32+d];
      grr += ar*br; gri += ar*bi; gir += ai*br; gii += ai*bi;
    }
    G2[(size_t)(((m*8+P)*4+i)*4+j)*8 + T] = f2(w*(grr+gii), w*(gir-gri));
    if (m == 0){
      int o = ((P*4+i)*4+j)*8 + T;
      Gdc[o] = grr; Gdc[1024+o] = gri; Gdc[2048+o] = gir; Gdc[3072+o] = gii;
    }
  }
}

// ---------------------------------------------------------------------------
// K3: attention logits via Parseval + softmax -> A.
// ---------------------------------------------------------------------------
__global__ __launch_bounds__(256) void attn_kernel(const float2* __restrict__ Vf,
                                                   const float2* __restrict__ G2,
                                                   const float* __restrict__ Gdc,
                                                   float* __restrict__ A){
  int bx = blockIdx.x;                 // (b<<8)|(hh<<5)|s
  int s = bx & 31;
  int base = ((bx >> 8) * 32) + (((bx >> 5) & 7) * 4);
  int tid = threadIdx.x;
  int t = tid & 31, mc = tid >> 5;
  __shared__ float2 s_vf[4][IN_CH][64];
  __shared__ float  s_part[8][33];
  for (int k = tid; k < 4*IN_CH*64; k += 256){
    int m = k & 63, c = (k>>6)&3, smp = k>>8;
    s_vf[smp][c][m] = Vf[((size_t)(base+smp)*IN_CH + c)*NM + m];
  }
  __syncthreads();
  int sg = s >> 3, P = s & 7;
  int tg = t >> 3, T = t & 7;
  float acc = 0.f;
  for (int mm = 0; mm < 8; ++mm){
    int m = mc*8 + mm;
    const float2* g = G2 + (size_t)((m*8+P)*16)*8 + T;
    float sub = 0.f;
    for (int i = 0; i < 4; ++i){
      float2 a = s_vf[sg][i][m];
      for (int j = 0; j < 4; ++j){
        float2 b = s_vf[tg][j][m];
        float zr = a.x*b.x + a.y*b.y;
        float zi = a.y*b.x - a.x*b.y;
        float2 gv = g[(size_t)(i*4+j)*8];
        sub += zr*gv.x - zi*gv.y;
      }
    }
    acc += sub;
  }
  if (mc == 0){
    float sub = 0.f;
    for (int i = 0; i < 4; ++i){
      float2 a = s_vf[sg][i][0];
      for (int j = 0; j < 4; ++j){
        float2 b = s_vf[tg][j][0];
        int o = ((P*4+i)*4+j)*8 + T;
        sub += a.x*b.x*Gdc[o] - a.x*b.y*Gdc[1024+o]
             - a.y*b.x*Gdc[2048+o] + a.y*b.y*Gdc[3072+o];
      }
    }
    acc += sub;
  }
  s_part[mc][t] = acc;
  __syncthreads();
  if (tid < 32){
    float l2 = 0.f;
    for (int k = 0; k < 8; ++k) l2 += s_part[k][tid];
    l2 *= 0.5f / (4096.0f * 4096.0f);
    float mx = l2;
    for (int off = 16; off; off >>= 1) mx = fmaxf(mx, __shfl_xor(mx, off, 32));
    float e = expf(l2 - mx);
    float sm = e;
    for (int off = 16; off; off >>= 1) sm += __shfl_xor(sm, off, 32);
    A[(size_t)bx*32 + tid] = e / sm;
  }
}

// ---------------------------------------------------------------------------
// K3b: transpose vw -> vwT[m][c][i] float2 (coalesced reads).
// ---------------------------------------------------------------------------
__global__ __launch_bounds__(256) void v1t_kernel(const float* __restrict__ vwr,
                                                  const float* __restrict__ vwi,
                                                  float2* __restrict__ vwT){
  int t = blockIdx.x*256 + threadIdx.x;   // 65536 = (i*256+c)*64 + m
  int m = t & 63, r = t >> 6, i = r >> 8, c = r & 255;
  vwT[((size_t)m*256 + c)*4 + i] = f2(vwr[t], vwi[t]);
}

// ---------------------------------------------------------------------------
// K4: fused vconv + attention-apply. Block per (b,hh,m-pair). Uf[n][m][c].
// ---------------------------------------------------------------------------
__global__ __launch_bounds__(256) void uspec_kernel(const float2* __restrict__ Vf,
                                                    const float2* __restrict__ vwT,
                                                    const float* __restrict__ A,
                                                    float2* __restrict__ Uf){
  int bid = blockIdx.x;                // b*256 + hh*32 + mg
  int mg = bid & 31, hh = (bid >> 5) & 7, b = bid >> 8;
  int m0 = mg*2;
  int nbase = b*32 + hh*4;
  int tid = threadIdx.x;
  __shared__ float2 s_vw[4][2][256];   // [i][mm][c]
  __shared__ float2 s_vv[4][2][256];   // [smp][mm][c]
  __shared__ float  s_A[32][33];
  __shared__ float2 s_vf[4][4][2];
  for (int k = tid; k < 2048; k += 256){
    int mm = k >> 10, c = (k >> 2) & 255, i = k & 3;
    s_vw[i][mm][c] = vwT[(size_t)m0*1024 + k];
  }
  for (int k = tid; k < 1024; k += 256)
    s_A[k>>5][k&31] = A[(size_t)((b*8+hh)*32 + (k>>5))*32 + (k&31)];
  if (tid < 32){
    int smp = tid >> 3, i = (tid >> 1) & 3, mm = tid & 1;
    s_vf[smp][i][mm] = Vf[((size_t)(nbase+smp)*4 + i)*64 + m0 + mm];
  }
  __syncthreads();
  for (int k = tid; k < 2048; k += 256){
    int smp = k >> 9, mm = (k >> 8) & 1, c = k & 255;
    float sr = 0.f, si = 0.f;
    for (int i = 0; i < 4; ++i){
      float2 v = s_vf[smp][i][mm];
      float2 w = s_vw[i][mm][c];
      sr += v.x*w.x - v.y*w.y;
      si += v.x*w.y + v.y*w.x;
    }
    s_vv[smp][mm][c] = f2(sr, si);
  }
  __syncthreads();
  int sg = tid >> 5, d = tid & 31;
  float2 acc[4][2];
  for (int ss = 0; ss < 4; ++ss)
    for (int mm = 0; mm < 2; ++mm) acc[ss][mm] = f2(0.f, 0.f);
  for (int tt = 0; tt < 32; ++tt){
    int tg = tt >> 3, c = (tt & 7)*32 + d;
    float a0 = s_A[sg*4+0][tt], a1 = s_A[sg*4+1][tt];
    float a2 = s_A[sg*4+2][tt], a3 = s_A[sg*4+3][tt];
    for (int mm = 0; mm < 2; ++mm){
      float2 v = s_vv[tg][mm][c];
      acc[0][mm].x += a0*v.x; acc[0][mm].y += a0*v.y;
      acc[1][mm].x += a1*v.x; acc[1][mm].y += a1*v.y;
      acc[2][mm].x += a2*v.x; acc[2][mm].y += a2*v.y;
      acc[3][mm].x += a3*v.x; acc[3][mm].y += a3*v.y;
    }
  }
  for (int ss = 0; ss < 4; ++ss){
    int n = b*32 + sg*4 + ss;
    for (int mm = 0; mm < 2; ++mm)
      Uf[((size_t)n*64 + m0 + mm)*256 + hh*32 + d] = acc[ss][mm];
  }
}

// ---------------------------------------------------------------------------
// K4b: u1w -> u1wT[m][c][o1] float4 {pr*wr, pi*wi, pr*wi, pi*wr}.
// ---------------------------------------------------------------------------
__global__ __launch_bounds__(256) void u1t_kernel(const float* __restrict__ u1wr,
                                                  const float* __restrict__ u1wi,
                                                  float4* __restrict__ u1wT){
  int t = blockIdx.x*256 + threadIdx.x;   // 524288 = (c*32+o1)*64 + m
  int m = t & 63, r = t >> 6, c = r >> 5, o1 = r & 31;
  float pr = ((m & 7)==0 && m) ? 0.5f : 1.0f;
  float pi = m ? pr : 0.0f;
  float wr = u1wr[t], wi = u1wi[t];
  u1wT[((size_t)m*256 + c)*32 + o1] = make_float4(pr*wr, pi*wi, pr*wi, pi*wr);
}

// ---------------------------------------------------------------------------
// K5: channel mixes. Block = (8 samples) x (2 modes); 256 thr.
// ---------------------------------------------------------------------------
__global__ __launch_bounds__(256) void mix1_kernel(const float2* __restrict__ Uf,
                                                   const float4* __restrict__ u1wT,
                                                   const float* __restrict__ s1w,
                                                   float2* __restrict__ U1f, float2* __restrict__ S1f){
  int bid = blockIdx.x;                // 256 = ng(8) x mg(32)
  int mg = bid & 31, n0 = (bid >> 5)*8, m0 = mg*2;
  int tid = threadIdx.x;
  __shared__ float2 s_u[8][2][256];    // [s][mm][c] : 32 KB
  __shared__ float  s_w1[32][257];     // padded: o1-major, conflict-free
  for (int it = 0; it < 16; ++it){
    int s = it >> 1, mm = it & 1;
    s_u[s][mm][tid] = Uf[((size_t)(n0+s)*64 + m0 + mm)*256 + tid];
  }
  for (int k = tid; k < 8192; k += 256)
    s_w1[k>>8][k&255] = s1w[k];
  __syncthreads();
  int o1 = tid & 31, mm = (tid >> 5) & 1, sh = tid >> 6;   // sh in 0..3
  int m = m0 + mm, sA = sh*2, sB = sh*2+1;
  const float4* wp = u1wT + (size_t)m*8192 + o1;
  float2 au0 = f2(0,0), au1 = f2(0,0), as0 = f2(0,0), as1 = f2(0,0);
  #pragma unroll 4
  for (int c = 0; c < 256; ++c){
    float4 w = wp[(size_t)c*32];
    float sw = s_w1[o1][c];
    float2 uA = s_u[sA][mm][c];
    float2 uB = s_u[sB][mm][c];
    au0.x += uA.x*w.x - uA.y*w.y;  au0.y += uA.x*w.z + uA.y*w.w;
    au1.x += uB.x*w.x - uB.y*w.y;  au1.y += uB.x*w.z + uB.y*w.w;
    as0.x += uA.x*sw;  as0.y += uA.y*sw;
    as1.x += uB.x*sw;  as1.y += uB.y*sw;
  }
  size_t obA = ((size_t)(n0+sA)*32 + o1)*64 + m;
  size_t obB = ((size_t)(n0+sB)*32 + o1)*64 + m;
  U1f[obA] = au0; S1f[obA] = as0;
  U1f[obB] = au1; S1f[obB] = as1;
}

// ---------------------------------------------------------------------------
// K6: Xg = DFT8x8( gelu( irfft(U1f) ) ), 2 fields/block, 512 threads.
// ---------------------------------------------------------------------------
__global__ __launch_bounds__(512) void xg_kernel(const float2* __restrict__ Etab,
                                                 const float2* __restrict__ U1f,
                                                 float2* __restrict__ Xg){
  int f0 = blockIdx.x*2, tid = threadIdx.x;
  __shared__ float2 s_e[64][8];
  __shared__ float2 s_eT[8][64];       // transposed copy: conflict-free ce hoist
  __shared__ float2 s_gu[2][64];
  __shared__ float2 s_tu[2][64][8];    // aliased as s_a1 after phase B
  __shared__ float  s_fld[2][64*68];
  if (tid < 512){
    float2 v = Etab[tid];
    int a = tid >> 3, b = tid & 7;
    s_e[a][b] = v; s_eT[b][a] = v;
  }
  if (tid < 128) ((float2*)s_gu)[tid] = U1f[(size_t)f0*NM + tid];
  __syncthreads();
  // phase A: y-transforms, 1024 items, 2/thread, split partials
  for (int o = tid; o < 1024; o += 512){
    int fl = o >> 9, r = o & 511, y = r >> 3, kx = r & 7;
    float wf = (kx ? 2.0f : 1.0f) * (1.0f/4096.0f);
    float a0=0.f, b0=0.f, a1=0.f, b1=0.f;
    for (int ky = 0; ky < 4; ++ky){
      float2 cs = s_e[y][ky];
      float2 gu = s_gu[fl][ky*8+kx];
      a0 += gu.x*cs.x - gu.y*cs.y;
      b0 += gu.x*cs.y + gu.y*cs.x;
    }
    for (int ky = 4; ky < 8; ++ky){
      float2 cs = s_e[y][ky];
      float2 gu = s_gu[fl][ky*8+kx];
      a1 += gu.x*cs.x - gu.y*cs.y;
      b1 += gu.x*cs.y + gu.y*cs.x;
    }
    s_tu[fl][y][kx] = f2((a0+a1)*wf, (b0+b1)*wf);
  }
  __syncthreads();
  // phase B: pixels + gelu, both fields
  int xx = tid & 63;
  float2 ce[8];
  #pragma unroll
  for (int k = 0; k < 8; ++k) ce[k] = s_eT[k][xx];
  for (int i = 0; i < 8; ++i){
    int p = i*512 + tid, y = p >> 6;   // wave-uniform y
    const float4* tp0 = (const float4*)&s_tu[0][y][0];
    const float4* tp1 = (const float4*)&s_tu[1][y][0];
    float4 a0=tp0[0], a1=tp0[1], a2=tp0[2], a3=tp0[3];
    float4 b0=tp1[0], b1=tp1[1], b2=tp1[2], b3=tp1[3];
    float h0 = a0.x*ce[0].x - a0.y*ce[0].y + a0.z*ce[1].x - a0.w*ce[1].y
             + a1.x*ce[2].x - a1.y*ce[2].y + a1.z*ce[3].x - a1.w*ce[3].y;
    float h1 = a2.x*ce[4].x - a2.y*ce[4].y + a2.z*ce[5].x - a2.w*ce[5].y
             + a3.x*ce[6].x - a3.y*ce[6].y + a3.z*ce[7].x - a3.w*ce[7].y;
    float k0 = b0.x*ce[0].x - b0.y*ce[0].y + b0.z*ce[1].x - b0.w*ce[1].y
             + b1.x*ce[2].x - b1.y*ce[2].y + b1.z*ce[3].x - b1.w*ce[3].y;
    float k1 = b2.x*ce[4].x - b2.y*ce[4].y + b2.z*ce[5].x - b2.w*ce[5].y
             + b3.x*ce[6].x - b3.y*ce[6].y + b3.z*ce[7].x - b3.w*ce[7].y;
    float v0 = h0 + h1, v1 = k0 + k1;
    float ga = 0.5f * v0 * (1.0f + erff(v0 * 0.70710678f));
    float gb = 0.5f * v1 * (1.0f + erff(v1 * 0.70710678f));
    s_fld[0][y*68 + xx] = ga;
    s_fld[1][y*68 + xx] = gb;
  }
  __syncthreads();
  // phase C: x-DFT stage 1 (writes alias s_tu)
  float2 (*s_a1)[64][8] = s_tu;
  for (int o = tid; o < 1024; o += 512){
    int fl = o >> 9, r = o & 511, y = r >> 3, kx = r & 7;
    const float4* row = (const float4*)&s_fld[fl][y*68];
    float sr0=0.f, si0=0.f, sr1=0.f, si1=0.f;
    for (int x4 = 0; x4 < 8; ++x4){
      float4 v = row[x4];
      int xb = x4*4;
      float2 c0 = s_e[xb+0][kx], c1 = s_e[xb+1][kx];
      float2 c2 = s_e[xb+2][kx], c3 = s_e[xb+3][kx];
      sr0 += v.x*c0.x + v.y*c1.x + v.z*c2.x + v.w*c3.x;
      si0 -= v.x*c0.y + v.y*c1.y + v.z*c2.y + v.w*c3.y;
    }
    for (int x4 = 8; x4 < 16; ++x4){
      float4 v = row[x4];
      int xb = x4*4;
      float2 c0 = s_e[xb+0][kx], c1 = s_e[xb+1][kx];
      float2 c2 = s_e[xb+2][kx], c3 = s_e[xb+3][kx];
      sr1 += v.x*c0.x + v.y*c1.x + v.z*c2.x + v.w*c3.x;
      si1 -= v.x*c0.y + v.y*c1.y + v.z*c2.y + v.w*c3.y;
    }
    s_a1[fl][y][kx] = f2(sr0+sr1, si0+si1);
  }
  __syncthreads();
  // phase D: y-DFT stage 2
  if (tid < 128){
    int fl = tid >> 6, t6 = tid & 63;
    int ky = t6 >> 3, kx = t6 & 7;
    float sr0=0.f, si0=0.f, sr1=0.f, si1=0.f;
    for (int y = 0; y < 32; ++y){
      float2 a = s_a1[fl][y][kx];
      float2 cs = s_e[y][ky];
      sr0 += a.x*cs.x + a.y*cs.y;
      si0 += a.y*cs.x - a.x*cs.y;
    }
    for (int y = 32; y < 64; ++y){
      float2 a = s_a1[fl][y][kx];
      float2 cs = s_e[y][ky];
      sr1 += a.x*cs.x + a.y*cs.y;
      si1 += a.y*cs.x - a.x*cs.y;
    }
    Xg[(size_t)(f0+fl)*NM + t6] = f2(sr0+sr1, si0+si1);
  }
}

// ---------------------------------------------------------------------------
// K7a: per-sample output spectrum (computed ONCE, not per pixel tile).
// OS[n][o2][m] = sum_o1 (Xg + P(S1f) + 4096*s1b*dc) * u2w  +  s2w * S1f
// Grid 64 blocks x 256 threads; thread = (o2, m).
// ---------------------------------------------------------------------------
__global__ __launch_bounds__(256) void final_spec_kernel(const float2* __restrict__ S1f,
                                                         const float2* __restrict__ Xg,
                                                         const float* __restrict__ u2wr, const float* __restrict__ u2wi,
                                                         const float* __restrict__ s1b,
                                                         const float* __restrict__ s2w,
                                                         float2* __restrict__ OS){
  int n = blockIdx.x, tid = threadIdx.x;
  __shared__ float s_w2[128], s_s1b[32];
  if (tid < 128) s_w2[tid] = s2w[tid];
  else if (tid < 160) s_s1b[tid-128] = s1b[tid-128];
  __syncthreads();
  int o2 = tid >> 6, m = tid & 63;
  float prm = ((m & 7)==0 && m) ? 0.5f : 1.0f;
  float pim = m ? prm : 0.0f;
  float dc = (m == 0) ? 4096.0f : 0.0f;
  float cr = 0.f, ci = 0.f;
  for (int o1 = 0; o1 < 32; ++o1){
    float2 xg = Xg[((size_t)n*32 + o1)*NM + m];
    float2 sf = S1f[((size_t)n*32 + o1)*NM + m];
    float Xr = xg.x + sf.x*prm + dc*s_s1b[o1];
    float Xi = xg.y + sf.y*pim;
    size_t wb = ((size_t)(o1*IN_CH + o2))*NM + m;
    float wr = u2wr[wb], wi = u2wi[wb];
    float sw = s_w2[o2*32 + o1];
    cr += Xr*wr - Xi*wi + sw*sf.x;
    ci += Xr*wi + Xi*wr + sw*sf.y;
  }
  OS[((size_t)n*IN_CH + o2)*NM + m] = f2(cr, ci);
}

// ---------------------------------------------------------------------------
// K7b: pixel kernel. out = irfft(OS) + s2 x gelu(irfft(U1f)) [recomputed] + b2
// + s2*s1b. Phases: u1 y-transform (tile rows), OS y-transform, pixels.
// ---------------------------------------------------------------------------
__global__ __launch_bounds__(256, 4) void final_kernel(const float2* __restrict__ Etab,
                                                       const float2* __restrict__ U1f,
                                                       const float2* __restrict__ OS,
                                                       const float* __restrict__ s1b,
                                                       const float* __restrict__ s2w, const float* __restrict__ s2b,
                                                       float* __restrict__ out){
  int n = blockIdx.x >> 4, tile = blockIdx.x & 15, y0 = tile*4;
  int tid = threadIdx.x;
  __shared__ float2 s_e[64][8];
  __shared__ float2 s_eT[8][64];
  __shared__ float2 s_u1[32][64];
  __shared__ float2 s_os[4][64];
  __shared__ float2 s_T[32][4][8];
  __shared__ float2 s_tmp[4][4][8];
  __shared__ float  s_w2[128], s_s1b[32], s_b2[4];
  for (int e = tid; e < 512; e += 256){
    float2 v = Etab[e];
    s_e[e>>3][e&7] = v; s_eT[e&7][e>>3] = v;
  }
  for (int k = tid; k < 2048; k += 256) ((float2*)s_u1)[k] = U1f[(size_t)n*2048 + k];
  if (tid < 128) s_w2[tid] = s2w[tid];
  else if (tid < 160) s_s1b[tid-128] = s1b[tid-128];
  else if (tid < 164) s_b2[tid-160] = s2b[tid-160];
  {
    int k = tid;
    if (k < 256) ((float2*)s_os)[k] = OS[(size_t)n*256 + k];
  }
  __syncthreads();
  // phase 1: per-channel y-transform for this tile's 4 rows
  for (int e = tid; e < 1024; e += 256){
    int c = e >> 5, yy = (e >> 3) & 3, kx = e & 7;
    int y = y0 + yy;
    float wf = (kx ? 2.0f : 1.0f) * (1.0f/4096.0f);
    float ar = 0.f, ai = 0.f;
    for (int ky = 0; ky < 8; ++ky){
      float2 cs = s_e[y][ky];
      float2 g = s_u1[c][ky*8+kx];
      ar += g.x*cs.x - g.y*cs.y;
      ai += g.x*cs.y + g.y*cs.x;
    }
    s_T[c][yy][kx] = f2(ar*wf, ai*wf);
  }
  // phase 3: OS y-transform (independent of phase 1; same barrier set)
  if (tid < 128){
    int o2 = tid >> 5, yy = (tid >> 3) & 3, kx = tid & 7;
    int y = y0 + yy;
    float wf = (kx ? 2.0f : 1.0f) * (1.0f/4096.0f);
    float tr=0.f, ti=0.f;
    for (int ky = 0; ky < 8; ++ky){
      float2 cs = s_e[y][ky];
      float2 g = s_os[o2][ky*8+kx];
      tr += g.x*cs.x - g.y*cs.y;
      ti += g.x*cs.y + g.y*cs.x;
    }
    s_tmp[o2][yy][kx] = f2(tr*wf, ti*wf);
  }
  __syncthreads();
  // phase 4: pixels (1 per thread)
  int yy = tid >> 6, xx = tid & 63;
  float2 ce[8];
  #pragma unroll
  for (int k = 0; k < 8; ++k) ce[k] = s_eT[k][xx];
  float a0 = s_b2[0], a1 = s_b2[1], a2 = s_b2[2], a3 = s_b2[3];
  for (int c = 0; c < 32; ++c){
    float b = s_s1b[c];
    a0 += s_w2[c]*b; a1 += s_w2[32+c]*b; a2 += s_w2[64+c]*b; a3 += s_w2[96+c]*b;
  }
  #pragma unroll 4
  for (int c = 0; c < 32; ++c){
    const float4* tp = (const float4*)&s_T[c][yy][0];
    float4 t0 = tp[0], t1 = tp[1], t2 = tp[2], t3 = tp[3];
    float h0 = t0.x*ce[0].x - t0.y*ce[0].y + t0.z*ce[1].x - t0.w*ce[1].y
             + t1.x*ce[2].x - t1.y*ce[2].y + t1.z*ce[3].x - t1.w*ce[3].y;
    float h1 = t2.x*ce[4].x - t2.y*ce[4].y + t2.z*ce[5].x - t2.w*ce[5].y
             + t3.x*ce[6].x - t3.y*ce[6].y + t3.z*ce[7].x - t3.w*ce[7].y;
    float vu = h0 + h1;
    float g = 0.5f * vu * (1.0f + erff(vu * 0.70710678f));
    a0 += s_w2[c]*g; a1 += s_w2[32+c]*g; a2 += s_w2[64+c]*g; a3 += s_w2[96+c]*g;
  }
  float sp[4];
  #pragma unroll
  for (int o2 = 0; o2 < 4; ++o2){
    const float4* tp = (const float4*)&s_tmp[o2][yy][0];
    float4 t0 = tp[0], t1 = tp[1], t2 = tp[2], t3 = tp[3];
    float h0 = t0.x*ce[0].x - t0.y*ce[0].y + t0.z*ce[1].x - t0.w*ce[1].y
             + t1.x*ce[2].x - t1.y*ce[2].y + t1.z*ce[3].x - t1.w*ce[3].y;
    float h1 = t2.x*ce[4].x - t2.y*ce[4].y + t2.z*ce[5].x - t2.w*ce[5].y
             + t3.x*ce[6].x - t3.y*ce[6].y + t3.z*ce[7].x - t3.w*ce[7].y;
    sp[o2] = h0 + h1;
  }
  int p = (y0 + yy)*64 + xx;
  float* ob = out + (size_t)n*IN_CH*NPIX;
  ob[p]          = a0 + sp[0];
  ob[NPIX + p]   = a1 + sp[1];
  ob[2*NPIX + p] = a2 + sp[2];
  ob[3*NPIX + p] = a3 + sp[3];
}

extern "C" void kernel_launch(void* const* d_in, const int* in_sizes, int n_in,
                              void* d_out, int out_size, void* d_ws, size_t ws_size,
                              hipStream_t stream) {
  (void)in_sizes; (void)n_in; (void)out_size; (void)ws_size;
  const float* v    = (const float*)d_in[0];
  const float* qwr  = (const float*)d_in[1];
  const float* qwi  = (const float*)d_in[2];
  const float* kwr  = (const float*)d_in[3];
  const float* kwi  = (const float*)d_in[4];
  const float* vwr  = (const float*)d_in[5];
  const float* vwi  = (const float*)d_in[6];
  const float* u1wr = (const float*)d_in[7];
  const float* u1wi = (const float*)d_in[8];
  const float* u2wr = (const float*)d_in[9];
  const float* u2wi = (const float*)d_in[10];
  const float* s1w  = (const float*)d_in[11];
  const float* s1b  = (const float*)d_in[12];
  const float* s2w  = (const float*)d_in[13];
  const float* s2b  = (const float*)d_in[14];
  float* out = (float*)d_out;

  float* ws = (float*)d_ws;
  size_t off = 0;
  float2* Etab =(float2*)(ws + off); off += 1024;
  float2* Vf   = (float2*)(ws + off); off += (size_t)NS*IN_CH*NM*2;     // 32768
  float2* G2   = (float2*)(ws + off); off += (size_t)65536*2;           // 131072
  float*  Gdc  =          (ws + off); off += 4096;
  float*  A    =          (ws + off); off += 16384;
  float2* Uf   = (float2*)(ws + off); off += (size_t)NS*NM*HD*2;        // 2097152
  float2* U1f  = (float2*)(ws + off); off += (size_t)NS*HIDC*NM*2;      // 262144
  float2* S1f  = (float2*)(ws + off); off += (size_t)NS*HIDC*NM*2;      // 262144
  float2* Xg   = (float2*)(ws + off); off += (size_t)NS*HIDC*NM*2;      // 262144
  float4* u1wT = (float4*)(ws + off); off += (size_t)524288*4;          // 2097152
  float2* vwT  = (float2*)(ws + off); off += (size_t)65536*2;           // 131072
  float2* OS   = (float2*)(ws + off); off += (size_t)NS*IN_CH*NM*2;     // 32768

  twiddle_kernel<<<1, 512, 0, stream>>>(Etab);
  fwd_dft_kernel<<<NS*IN_CH, 512, 0, stream>>>(v, Etab, Vf);
  gram_kernel<<<64, 256, 0, stream>>>(qwr, qwi, kwr, kwi, G2, Gdc);
  u1t_kernel<<<2048, 256, 0, stream>>>(u1wr, u1wi, u1wT);
  v1t_kernel<<<256, 256, 0, stream>>>(vwr, vwi, vwT);
  attn_kernel<<<512, 256, 0, stream>>>(Vf, G2, Gdc, A);
  uspec_kernel<<<512, 256, 0, stream>>>(Vf, vwT, A, Uf);
  mix1_kernel<<<256, 256, 0, stream>>>(Uf, u1wT, s1w, U1f, S1f);
  xg_kernel<<<1024, 512, 0, stream>>>(Etab, U1f, Xg);
  final_spec_kernel<<<NS, 256, 0, stream>>>(S1f, Xg, u2wr, u2wi, s1b, s2w, OS);
  final_kernel<<<NS*16, 256, 0, stream>>>(Etab, U1f, OS, s1b, s2w, s2b, out);
}

// Round 10
// 200.542 us; speedup vs baseline: 1.1988x; 1.0395x over previous
//
#include <hip/hip_runtime.h>
#include <math.h>

#define HEADS 8
#define HIDC  32
#define MODES 8
#define IN_CH 4
#define SEQ   32
#define NS    64      // B*SEQ samples
#define HD    256     // HEADS*HIDC
#define NM    64      // MODES*MODES
#define NPIX  4096    // 64*64
#define TWO_PI_D 6.283185307179586476925286766559

__device__ __forceinline__ float2 f2(float a, float b){ return make_float2(a,b); }

// ---------------------------------------------------------------------------
// K-prep: fused weight preparation, partitioned by blockIdx:
//   block 0        : Etab twiddle table
//   blocks 1..64   : gram (m = bid-1)
//   blocks 65..320 : vwT transpose
//   blocks 321..2368: u1wT transpose (projection folded)
// ---------------------------------------------------------------------------
__global__ __launch_bounds__(256) void prep_kernel(const float* __restrict__ qwr, const float* __restrict__ qwi,
                                                   const float* __restrict__ kwr, const float* __restrict__ kwi,
                                                   const float* __restrict__ vwr, const float* __restrict__ vwi,
                                                   const float* __restrict__ u1wr, const float* __restrict__ u1wi,
                                                   float2* __restrict__ Etab,
                                                   float2* __restrict__ G2, float* __restrict__ Gdc,
                                                   float2* __restrict__ vwT,
                                                   float4* __restrict__ u1wT){
  int bid = blockIdx.x, tid = threadIdx.x;
  if (bid == 0){
    for (int t = tid; t < 512; t += 256){
      int a = t >> 3, b = t & 7;
      double sv, cv; sincos(TWO_PI_D * ((a*b) & 63) / 64.0, &sv, &cv);
      Etab[t] = f2((float)cv, (float)sv);
    }
    return;
  }
  if (bid <= 64){
    int m = bid - 1;
    __shared__ float qsr[4][257], qsi[4][257], ksr[4][257], ksi[4][257];
    for (int k = tid; k < 1024; k += 256){
      int i = k >> 8, c = k & 255;
      size_t a = ((size_t)(i*256 + c))*64 + m;
      qsr[i][c] = qwr[a]; qsi[i][c] = qwi[a];
      ksr[i][c] = kwr[a]; ksi[i][c] = kwi[a];
    }
    __syncthreads();
    int kx = m & 7, ky = m >> 3;
    float w = (kx >= 1) ? 2.0f : ((ky >= 1) ? 0.5f : 0.0f);
    for (int e = tid; e < 1024; e += 256){
      int P = e >> 7, T = (e >> 4) & 7, i = (e >> 2) & 3, j = e & 3;
      float grr=0.f, gri=0.f, gir=0.f, gii=0.f;
      for (int d = 0; d < 32; ++d){
        float ar = qsr[i][P*32+d], ai = qsi[i][P*32+d];
        float br = ksr[j][T*32+d], bi = ksi[j][T*32+d];
        grr += ar*br; gri += ar*bi; gir += ai*br; gii += ai*bi;
      }
      G2[(size_t)(((m*8+P)*4+i)*4+j)*8 + T] = f2(w*(grr+gii), w*(gir-gri));
      if (m == 0){
        int o = ((P*4+i)*4+j)*8 + T;
        Gdc[o] = grr; Gdc[1024+o] = gri; Gdc[2048+o] = gir; Gdc[3072+o] = gii;
      }
    }
    return;
  }
  if (bid <= 320){
    int t = (bid - 65)*256 + tid;     // 65536 = (i*256+c)*64 + m
    int m = t & 63, r = t >> 6, i = r >> 8, c = r & 255;
    vwT[((size_t)m*256 + c)*4 + i] = f2(vwr[t], vwi[t]);
    return;
  }
  {
    int t = (bid - 321)*256 + tid;    // 524288 = (c*32+o1)*64 + m
    int m = t & 63, r = t >> 6, c = r >> 5, o1 = r & 31;
    float pr = ((m & 7)==0 && m) ? 0.5f : 1.0f;
    float pi = m ? pr : 0.0f;
    float wr = u1wr[t], wi = u1wi[t];
    u1wT[((size_t)m*256 + c)*32 + o1] = make_float4(pr*wr, pi*wi, pr*wi, pi*wr);
  }
}

// ---------------------------------------------------------------------------
// K1: partial forward DFT of v: per field [64][64] -> 8x8 low modes.
// ---------------------------------------------------------------------------
__global__ __launch_bounds__(512) void fwd_dft_kernel(const float* __restrict__ src,
                                                      const float2* __restrict__ Etab,
                                                      float2* __restrict__ dst){
  int f = blockIdx.x, tid = threadIdx.x;
  __shared__ float  s_fld[64*68];
  __shared__ float2 s_e[64][8];
  __shared__ float2 s_a1[64][8];
  if (tid < 512) ((float2*)s_e)[tid] = Etab[tid];
  const float4* f4 = (const float4*)(src + (size_t)f*NPIX);
  for (int k = tid; k < 1024; k += 512){
    float4 v = f4[k];
    int y = k >> 4, x4 = (k & 15)*4;
    float* row = &s_fld[y*68 + x4];
    row[0]=v.x; row[1]=v.y; row[2]=v.z; row[3]=v.w;
  }
  __syncthreads();
  {
    int y = tid >> 3, kx = tid & 7;
    const float4* row = (const float4*)&s_fld[y*68];
    float sr0=0.f, si0=0.f, sr1=0.f, si1=0.f;
    for (int x4 = 0; x4 < 8; ++x4){
      float4 v = row[x4];
      int xb = x4*4;
      float2 c0 = s_e[xb+0][kx], c1 = s_e[xb+1][kx];
      float2 c2 = s_e[xb+2][kx], c3 = s_e[xb+3][kx];
      sr0 += v.x*c0.x + v.y*c1.x + v.z*c2.x + v.w*c3.x;
      si0 -= v.x*c0.y + v.y*c1.y + v.z*c2.y + v.w*c3.y;
    }
    for (int x4 = 8; x4 < 16; ++x4){
      float4 v = row[x4];
      int xb = x4*4;
      float2 c0 = s_e[xb+0][kx], c1 = s_e[xb+1][kx];
      float2 c2 = s_e[xb+2][kx], c3 = s_e[xb+3][kx];
      sr1 += v.x*c0.x + v.y*c1.x + v.z*c2.x + v.w*c3.x;
      si1 -= v.x*c0.y + v.y*c1.y + v.z*c2.y + v.w*c3.y;
    }
    s_a1[y][kx] = f2(sr0+sr1, si0+si1);
  }
  __syncthreads();
  if (tid < 64){
    int ky = tid >> 3, kx = tid & 7;
    float sr0=0.f, si0=0.f, sr1=0.f, si1=0.f;
    for (int y = 0; y < 32; ++y){
      float2 a = s_a1[y][kx];
      float2 cs = s_e[y][ky];
      sr0 += a.x*cs.x + a.y*cs.y;
      si0 += a.y*cs.x - a.x*cs.y;
    }
    for (int y = 32; y < 64; ++y){
      float2 a = s_a1[y][kx];
      float2 cs = s_e[y][ky];
      sr1 += a.x*cs.x + a.y*cs.y;
      si1 += a.y*cs.x - a.x*cs.y;
    }
    dst[(size_t)f*NM + tid] = f2(sr0+sr1, si0+si1);
  }
}

// ---------------------------------------------------------------------------
// K3: attention logits via Parseval + softmax -> A.
// ---------------------------------------------------------------------------
__global__ __launch_bounds__(256) void attn_kernel(const float2* __restrict__ Vf,
                                                   const float2* __restrict__ G2,
                                                   const float* __restrict__ Gdc,
                                                   float* __restrict__ A){
  int bx = blockIdx.x;                 // (b<<8)|(hh<<5)|s
  int s = bx & 31;
  int base = ((bx >> 8) * 32) + (((bx >> 5) & 7) * 4);
  int tid = threadIdx.x;
  int t = tid & 31, mc = tid >> 5;
  __shared__ float2 s_vf[4][IN_CH][64];
  __shared__ float  s_part[8][33];
  for (int k = tid; k < 4*IN_CH*64; k += 256){
    int m = k & 63, c = (k>>6)&3, smp = k>>8;
    s_vf[smp][c][m] = Vf[((size_t)(base+smp)*IN_CH + c)*NM + m];
  }
  __syncthreads();
  int sg = s >> 3, P = s & 7;
  int tg = t >> 3, T = t & 7;
  float acc = 0.f;
  for (int mm = 0; mm < 8; ++mm){
    int m = mc*8 + mm;
    const float2* g = G2 + (size_t)((m*8+P)*16)*8 + T;
    float sub = 0.f;
    for (int i = 0; i < 4; ++i){
      float2 a = s_vf[sg][i][m];
      for (int j = 0; j < 4; ++j){
        float2 b = s_vf[tg][j][m];
        float zr = a.x*b.x + a.y*b.y;
        float zi = a.y*b.x - a.x*b.y;
        float2 gv = g[(size_t)(i*4+j)*8];
        sub += zr*gv.x - zi*gv.y;
      }
    }
    acc += sub;
  }
  if (mc == 0){
    float sub = 0.f;
    for (int i = 0; i < 4; ++i){
      float2 a = s_vf[sg][i][0];
      for (int j = 0; j < 4; ++j){
        float2 b = s_vf[tg][j][0];
        int o = ((P*4+i)*4+j)*8 + T;
        sub += a.x*b.x*Gdc[o] - a.x*b.y*Gdc[1024+o]
             - a.y*b.x*Gdc[2048+o] + a.y*b.y*Gdc[3072+o];
      }
    }
    acc += sub;
  }
  s_part[mc][t] = acc;
  __syncthreads();
  if (tid < 32){
    float l2 = 0.f;
    for (int k = 0; k < 8; ++k) l2 += s_part[k][tid];
    l2 *= 0.5f / (4096.0f * 4096.0f);
    float mx = l2;
    for (int off = 16; off; off >>= 1) mx = fmaxf(mx, __shfl_xor(mx, off, 32));
    float e = expf(l2 - mx);
    float sm = e;
    for (int off = 16; off; off >>= 1) sm += __shfl_xor(sm, off, 32);
    A[(size_t)bx*32 + tid] = e / sm;
  }
}

// ---------------------------------------------------------------------------
// K4: fused vconv + attention-apply. Block per (b,hh,m-pair). Uf[n][m][c].
// ---------------------------------------------------------------------------
__global__ __launch_bounds__(256) void uspec_kernel(const float2* __restrict__ Vf,
                                                    const float2* __restrict__ vwT,
                                                    const float* __restrict__ A,
                                                    float2* __restrict__ Uf){
  int bid = blockIdx.x;                // b*256 + hh*32 + mg
  int mg = bid & 31, hh = (bid >> 5) & 7, b = bid >> 8;
  int m0 = mg*2;
  int nbase = b*32 + hh*4;
  int tid = threadIdx.x;
  __shared__ float2 s_vw[4][2][256];   // [i][mm][c]
  __shared__ float2 s_vv[4][2][256];   // [smp][mm][c]
  __shared__ float  s_A[32][33];
  __shared__ float2 s_vf[4][4][2];
  for (int k = tid; k < 2048; k += 256){
    int mm = k >> 10, c = (k >> 2) & 255, i = k & 3;
    s_vw[i][mm][c] = vwT[(size_t)m0*1024 + k];
  }
  for (int k = tid; k < 1024; k += 256)
    s_A[k>>5][k&31] = A[(size_t)((b*8+hh)*32 + (k>>5))*32 + (k&31)];
  if (tid < 32){
    int smp = tid >> 3, i = (tid >> 1) & 3, mm = tid & 1;
    s_vf[smp][i][mm] = Vf[((size_t)(nbase+smp)*4 + i)*64 + m0 + mm];
  }
  __syncthreads();
  for (int k = tid; k < 2048; k += 256){
    int smp = k >> 9, mm = (k >> 8) & 1, c = k & 255;
    float sr = 0.f, si = 0.f;
    for (int i = 0; i < 4; ++i){
      float2 v = s_vf[smp][i][mm];
      float2 w = s_vw[i][mm][c];
      sr += v.x*w.x - v.y*w.y;
      si += v.x*w.y + v.y*w.x;
    }
    s_vv[smp][mm][c] = f2(sr, si);
  }
  __syncthreads();
  int sg = tid >> 5, d = tid & 31;
  float2 acc[4][2];
  for (int ss = 0; ss < 4; ++ss)
    for (int mm = 0; mm < 2; ++mm) acc[ss][mm] = f2(0.f, 0.f);
  for (int tt = 0; tt < 32; ++tt){
    int tg = tt >> 3, c = (tt & 7)*32 + d;
    float a0 = s_A[sg*4+0][tt], a1 = s_A[sg*4+1][tt];
    float a2 = s_A[sg*4+2][tt], a3 = s_A[sg*4+3][tt];
    for (int mm = 0; mm < 2; ++mm){
      float2 v = s_vv[tg][mm][c];
      acc[0][mm].x += a0*v.x; acc[0][mm].y += a0*v.y;
      acc[1][mm].x += a1*v.x; acc[1][mm].y += a1*v.y;
      acc[2][mm].x += a2*v.x; acc[2][mm].y += a2*v.y;
      acc[3][mm].x += a3*v.x; acc[3][mm].y += a3*v.y;
    }
  }
  for (int ss = 0; ss < 4; ++ss){
    int n = b*32 + sg*4 + ss;
    for (int mm = 0; mm < 2; ++mm)
      Uf[((size_t)n*64 + m0 + mm)*256 + hh*32 + d] = acc[ss][mm];
  }
}

// ---------------------------------------------------------------------------
// K5: channel mixes. Block = (8 samples) x (2 modes); 256 thr.
// ---------------------------------------------------------------------------
__global__ __launch_bounds__(256) void mix1_kernel(const float2* __restrict__ Uf,
                                                   const float4* __restrict__ u1wT,
                                                   const float* __restrict__ s1w,
                                                   float2* __restrict__ U1f, float2* __restrict__ S1f){
  int bid = blockIdx.x;                // 256 = ng(8) x mg(32)
  int mg = bid & 31, n0 = (bid >> 5)*8, m0 = mg*2;
  int tid = threadIdx.x;
  __shared__ float2 s_u[8][2][256];    // [s][mm][c] : 32 KB
  __shared__ float  s_w1[32][257];     // padded: o1-major, conflict-free
  for (int it = 0; it < 16; ++it){
    int s = it >> 1, mm = it & 1;
    s_u[s][mm][tid] = Uf[((size_t)(n0+s)*64 + m0 + mm)*256 + tid];
  }
  for (int k = tid; k < 8192; k += 256)
    s_w1[k>>8][k&255] = s1w[k];
  __syncthreads();
  int o1 = tid & 31, mm = (tid >> 5) & 1, sh = tid >> 6;   // sh in 0..3
  int m = m0 + mm, sA = sh*2, sB = sh*2+1;
  const float4* wp = u1wT + (size_t)m*8192 + o1;
  float2 au0 = f2(0,0), au1 = f2(0,0), as0 = f2(0,0), as1 = f2(0,0);
  #pragma unroll 4
  for (int c = 0; c < 256; ++c){
    float4 w = wp[(size_t)c*32];
    float sw = s_w1[o1][c];
    float2 uA = s_u[sA][mm][c];
    float2 uB = s_u[sB][mm][c];
    au0.x += uA.x*w.x - uA.y*w.y;  au0.y += uA.x*w.z + uA.y*w.w;
    au1.x += uB.x*w.x - uB.y*w.y;  au1.y += uB.x*w.z + uB.y*w.w;
    as0.x += uA.x*sw;  as0.y += uA.y*sw;
    as1.x += uB.x*sw;  as1.y += uB.y*sw;
  }
  size_t obA = ((size_t)(n0+sA)*32 + o1)*64 + m;
  size_t obB = ((size_t)(n0+sB)*32 + o1)*64 + m;
  U1f[obA] = au0; S1f[obA] = as0;
  U1f[obB] = au1; S1f[obB] = as1;
}

// ---------------------------------------------------------------------------
// K6: Xg = DFT8x8( gelu( irfft(U1f) ) ), 2 fields/block, 512 threads.
// ---------------------------------------------------------------------------
__global__ __launch_bounds__(512) void xg_kernel(const float2* __restrict__ Etab,
                                                 const float2* __restrict__ U1f,
                                                 float2* __restrict__ Xg){
  int f0 = blockIdx.x*2, tid = threadIdx.x;
  __shared__ float2 s_e[64][8];
  __shared__ float2 s_eT[8][64];       // transposed copy: conflict-free ce hoist
  __shared__ float2 s_gu[2][64];
  __shared__ float2 s_tu[2][64][8];    // aliased as s_a1 after phase B
  __shared__ float  s_fld[2][64*68];
  if (tid < 512){
    float2 v = Etab[tid];
    int a = tid >> 3, b = tid & 7;
    s_e[a][b] = v; s_eT[b][a] = v;
  }
  if (tid < 128) ((float2*)s_gu)[tid] = U1f[(size_t)f0*NM + tid];
  __syncthreads();
  for (int o = tid; o < 1024; o += 512){
    int fl = o >> 9, r = o & 511, y = r >> 3, kx = r & 7;
    float wf = (kx ? 2.0f : 1.0f) * (1.0f/4096.0f);
    float a0=0.f, b0=0.f, a1=0.f, b1=0.f;
    for (int ky = 0; ky < 4; ++ky){
      float2 cs = s_e[y][ky];
      float2 gu = s_gu[fl][ky*8+kx];
      a0 += gu.x*cs.x - gu.y*cs.y;
      b0 += gu.x*cs.y + gu.y*cs.x;
    }
    for (int ky = 4; ky < 8; ++ky){
      float2 cs = s_e[y][ky];
      float2 gu = s_gu[fl][ky*8+kx];
      a1 += gu.x*cs.x - gu.y*cs.y;
      b1 += gu.x*cs.y + gu.y*cs.x;
    }
    s_tu[fl][y][kx] = f2((a0+a1)*wf, (b0+b1)*wf);
  }
  __syncthreads();
  int xx = tid & 63;
  float2 ce[8];
  #pragma unroll
  for (int k = 0; k < 8; ++k) ce[k] = s_eT[k][xx];
  for (int i = 0; i < 8; ++i){
    int p = i*512 + tid, y = p >> 6;   // wave-uniform y
    const float4* tp0 = (const float4*)&s_tu[0][y][0];
    const float4* tp1 = (const float4*)&s_tu[1][y][0];
    float4 a0=tp0[0], a1=tp0[1], a2=tp0[2], a3=tp0[3];
    float4 b0=tp1[0], b1=tp1[1], b2=tp1[2], b3=tp1[3];
    float h0 = a0.x*ce[0].x - a0.y*ce[0].y + a0.z*ce[1].x - a0.w*ce[1].y
             + a1.x*ce[2].x - a1.y*ce[2].y + a1.z*ce[3].x - a1.w*ce[3].y;
    float h1 = a2.x*ce[4].x - a2.y*ce[4].y + a2.z*ce[5].x - a2.w*ce[5].y
             + a3.x*ce[6].x - a3.y*ce[6].y + a3.z*ce[7].x - a3.w*ce[7].y;
    float k0 = b0.x*ce[0].x - b0.y*ce[0].y + b0.z*ce[1].x - b0.w*ce[1].y
             + b1.x*ce[2].x - b1.y*ce[2].y + b1.z*ce[3].x - b1.w*ce[3].y;
    float k1 = b2.x*ce[4].x - b2.y*ce[4].y + b2.z*ce[5].x - b2.w*ce[5].y
             + b3.x*ce[6].x - b3.y*ce[6].y + b3.z*ce[7].x - b3.w*ce[7].y;
    float v0 = h0 + h1, v1 = k0 + k1;
    float ga = 0.5f * v0 * (1.0f + erff(v0 * 0.70710678f));
    float gb = 0.5f * v1 * (1.0f + erff(v1 * 0.70710678f));
    s_fld[0][y*68 + xx] = ga;
    s_fld[1][y*68 + xx] = gb;
  }
  __syncthreads();
  float2 (*s_a1)[64][8] = s_tu;
  for (int o = tid; o < 1024; o += 512){
    int fl = o >> 9, r = o & 511, y = r >> 3, kx = r & 7;
    const float4* row = (const float4*)&s_fld[fl][y*68];
    float sr0=0.f, si0=0.f, sr1=0.f, si1=0.f;
    for (int x4 = 0; x4 < 8; ++x4){
      float4 v = row[x4];
      int xb = x4*4;
      float2 c0 = s_e[xb+0][kx], c1 = s_e[xb+1][kx];
      float2 c2 = s_e[xb+2][kx], c3 = s_e[xb+3][kx];
      sr0 += v.x*c0.x + v.y*c1.x + v.z*c2.x + v.w*c3.x;
      si0 -= v.x*c0.y + v.y*c1.y + v.z*c2.y + v.w*c3.y;
    }
    for (int x4 = 8; x4 < 16; ++x4){
      float4 v = row[x4];
      int xb = x4*4;
      float2 c0 = s_e[xb+0][kx], c1 = s_e[xb+1][kx];
      float2 c2 = s_e[xb+2][kx], c3 = s_e[xb+3][kx];
      sr1 += v.x*c0.x + v.y*c1.x + v.z*c2.x + v.w*c3.x;
      si1 -= v.x*c0.y + v.y*c1.y + v.z*c2.y + v.w*c3.y;
    }
    s_a1[fl][y][kx] = f2(sr0+sr1, si0+si1);
  }
  __syncthreads();
  if (tid < 128){
    int fl = tid >> 6, t6 = tid & 63;
    int ky = t6 >> 3, kx = t6 & 7;
    float sr0=0.f, si0=0.f, sr1=0.f, si1=0.f;
    for (int y = 0; y < 32; ++y){
      float2 a = s_a1[fl][y][kx];
      float2 cs = s_e[y][ky];
      sr0 += a.x*cs.x + a.y*cs.y;
      si0 += a.y*cs.x - a.x*cs.y;
    }
    for (int y = 32; y < 64; ++y){
      float2 a = s_a1[fl][y][kx];
      float2 cs = s_e[y][ky];
      sr1 += a.x*cs.x + a.y*cs.y;
      si1 += a.y*cs.x - a.x*cs.y;
    }
    Xg[(size_t)(f0+fl)*NM + t6] = f2(sr0+sr1, si0+si1);
  }
}

// ---------------------------------------------------------------------------
// K7a: per-sample output spectrum (once per sample).
// ---------------------------------------------------------------------------
__global__ __launch_bounds__(256) void final_spec_kernel(const float2* __restrict__ S1f,
                                                         const float2* __restrict__ Xg,
                                                         const float* __restrict__ u2wr, const float* __restrict__ u2wi,
                                                         const float* __restrict__ s1b,
                                                         const float* __restrict__ s2w,
                                                         float2* __restrict__ OS){
  int n = blockIdx.x, tid = threadIdx.x;
  __shared__ float s_w2[128], s_s1b[32];
  if (tid < 128) s_w2[tid] = s2w[tid];
  else if (tid < 160) s_s1b[tid-128] = s1b[tid-128];
  __syncthreads();
  int o2 = tid >> 6, m = tid & 63;
  float prm = ((m & 7)==0 && m) ? 0.5f : 1.0f;
  float pim = m ? prm : 0.0f;
  float dc = (m == 0) ? 4096.0f : 0.0f;
  float cr = 0.f, ci = 0.f;
  for (int o1 = 0; o1 < 32; ++o1){
    float2 xg = Xg[((size_t)n*32 + o1)*NM + m];
    float2 sf = S1f[((size_t)n*32 + o1)*NM + m];
    float Xr = xg.x + sf.x*prm + dc*s_s1b[o1];
    float Xi = xg.y + sf.y*pim;
    size_t wb = ((size_t)(o1*IN_CH + o2))*NM + m;
    float wr = u2wr[wb], wi = u2wi[wb];
    float sw = s_w2[o2*32 + o1];
    cr += Xr*wr - Xi*wi + sw*sf.x;
    ci += Xr*wi + Xi*wr + sw*sf.y;
  }
  OS[((size_t)n*IN_CH + o2)*NM + m] = f2(cr, ci);
}

// ---------------------------------------------------------------------------
// K7b: pixel kernel, 8-row tiles, 512 threads, 1 px/thread.
// ---------------------------------------------------------------------------
__global__ __launch_bounds__(512) void final_kernel(const float2* __restrict__ Etab,
                                                    const float2* __restrict__ U1f,
                                                    const float2* __restrict__ OS,
                                                    const float* __restrict__ s1b,
                                                    const float* __restrict__ s2w, const float* __restrict__ s2b,
                                                    float* __restrict__ out){
  int n = blockIdx.x >> 3, tile = blockIdx.x & 7, y0 = tile*8;
  int tid = threadIdx.x;
  __shared__ float2 s_e[64][8];
  __shared__ float2 s_eT[8][64];
  __shared__ float2 s_u1[32][64];
  __shared__ float2 s_os[4][64];
  __shared__ float2 s_T[32][8][8];
  __shared__ float2 s_tmp[4][8][8];
  __shared__ float  s_w2[128], s_s1b[32], s_b2[4];
  if (tid < 512){
    float2 v = Etab[tid];
    s_e[tid>>3][tid&7] = v; s_eT[tid&7][tid>>3] = v;
  }
  for (int k = tid; k < 2048; k += 512) ((float2*)s_u1)[k] = U1f[(size_t)n*2048 + k];
  if (tid < 256) ((float2*)s_os)[tid] = OS[(size_t)n*256 + tid];
  else if (tid < 384) s_w2[tid-256] = s2w[tid-256];
  else if (tid < 416) s_s1b[tid-384] = s1b[tid-384];
  else if (tid < 420) s_b2[tid-416] = s2b[tid-416];
  __syncthreads();
  // phase 1: per-channel y-transform, this tile's 8 rows (2048 items)
  for (int e = tid; e < 2048; e += 512){
    int c = e >> 6, yy = (e >> 3) & 7, kx = e & 7;
    int y = y0 + yy;
    float wf = (kx ? 2.0f : 1.0f) * (1.0f/4096.0f);
    float ar = 0.f, ai = 0.f;
    for (int ky = 0; ky < 8; ++ky){
      float2 cs = s_e[y][ky];
      float2 g = s_u1[c][ky*8+kx];
      ar += g.x*cs.x - g.y*cs.y;
      ai += g.x*cs.y + g.y*cs.x;
    }
    s_T[c][yy][kx] = f2(ar*wf, ai*wf);
  }
  // phase 3: OS y-transform (256 items)
  if (tid < 256){
    int o2 = tid >> 6, yy = (tid >> 3) & 7, kx = tid & 7;
    int y = y0 + yy;
    float wf = (kx ? 2.0f : 1.0f) * (1.0f/4096.0f);
    float tr=0.f, ti=0.f;
    for (int ky = 0; ky < 8; ++ky){
      float2 cs = s_e[y][ky];
      float2 g = s_os[o2][ky*8+kx];
      tr += g.x*cs.x - g.y*cs.y;
      ti += g.x*cs.y + g.y*cs.x;
    }
    s_tmp[o2][yy][kx] = f2(tr*wf, ti*wf);
  }
  __syncthreads();
  // phase 4: pixels (1 per thread)
  int yy = tid >> 6, xx = tid & 63;
  float2 ce[8];
  #pragma unroll
  for (int k = 0; k < 8; ++k) ce[k] = s_eT[k][xx];
  float a0 = s_b2[0], a1 = s_b2[1], a2 = s_b2[2], a3 = s_b2[3];
  for (int c = 0; c < 32; ++c){
    float b = s_s1b[c];
    a0 += s_w2[c]*b; a1 += s_w2[32+c]*b; a2 += s_w2[64+c]*b; a3 += s_w2[96+c]*b;
  }
  #pragma unroll 4
  for (int c = 0; c < 32; ++c){
    const float4* tp = (const float4*)&s_T[c][yy][0];
    float4 t0 = tp[0], t1 = tp[1], t2 = tp[2], t3 = tp[3];
    float h0 = t0.x*ce[0].x - t0.y*ce[0].y + t0.z*ce[1].x - t0.w*ce[1].y
             + t1.x*ce[2].x - t1.y*ce[2].y + t1.z*ce[3].x - t1.w*ce[3].y;
    float h1 = t2.x*ce[4].x - t2.y*ce[4].y + t2.z*ce[5].x - t2.w*ce[5].y
             + t3.x*ce[6].x - t3.y*ce[6].y + t3.z*ce[7].x - t3.w*ce[7].y;
    float vu = h0 + h1;
    float g = 0.5f * vu * (1.0f + erff(vu * 0.70710678f));
    a0 += s_w2[c]*g; a1 += s_w2[32+c]*g; a2 += s_w2[64+c]*g; a3 += s_w2[96+c]*g;
  }
  float sp[4];
  #pragma unroll
  for (int o2 = 0; o2 < 4; ++o2){
    const float4* tp = (const float4*)&s_tmp[o2][yy][0];
    float4 t0 = tp[0], t1 = tp[1], t2 = tp[2], t3 = tp[3];
    float h0 = t0.x*ce[0].x - t0.y*ce[0].y + t0.z*ce[1].x - t0.w*ce[1].y
             + t1.x*ce[2].x - t1.y*ce[2].y + t1.z*ce[3].x - t1.w*ce[3].y;
    float h1 = t2.x*ce[4].x - t2.y*ce[4].y + t2.z*ce[5].x - t2.w*ce[5].y
             + t3.x*ce[6].x - t3.y*ce[6].y + t3.z*ce[7].x - t3.w*ce[7].y;
    sp[o2] = h0 + h1;
  }
  int p = (y0 + yy)*64 + xx;
  float* ob = out + (size_t)n*IN_CH*NPIX;
  ob[p]          = a0 + sp[0];
  ob[NPIX + p]   = a1 + sp[1];
  ob[2*NPIX + p] = a2 + sp[2];
  ob[3*NPIX + p] = a3 + sp[3];
}

extern "C" void kernel_launch(void* const* d_in, const int* in_sizes, int n_in,
                              void* d_out, int out_size, void* d_ws, size_t ws_size,
                              hipStream_t stream) {
  (void)in_sizes; (void)n_in; (void)out_size; (void)ws_size;
  const float* v    = (const float*)d_in[0];
  const float* qwr  = (const float*)d_in[1];
  const float* qwi  = (const float*)d_in[2];
  const float* kwr  = (const float*)d_in[3];
  const float* kwi  = (const float*)d_in[4];
  const float* vwr  = (const float*)d_in[5];
  const float* vwi  = (const float*)d_in[6];
  const float* u1wr = (const float*)d_in[7];
  const float* u1wi = (const float*)d_in[8];
  const float* u2wr = (const float*)d_in[9];
  const float* u2wi = (const float*)d_in[10];
  const float* s1w  = (const float*)d_in[11];
  const float* s1b  = (const float*)d_in[12];
  const float* s2w  = (const float*)d_in[13];
  const float* s2b  = (const float*)d_in[14];
  float* out = (float*)d_out;

  float* ws = (float*)d_ws;
  size_t off = 0;
  float2* Etab =(float2*)(ws + off); off += 1024;
  float2* Vf   = (float2*)(ws + off); off += (size_t)NS*IN_CH*NM*2;     // 32768
  float2* G2   = (float2*)(ws + off); off += (size_t)65536*2;           // 131072
  float*  Gdc  =          (ws + off); off += 4096;
  float*  A    =          (ws + off); off += 16384;
  float2* Uf   = (float2*)(ws + off); off += (size_t)NS*NM*HD*2;        // 2097152
  float2* U1f  = (float2*)(ws + off); off += (size_t)NS*HIDC*NM*2;      // 262144
  float2* S1f  = (float2*)(ws + off); off += (size_t)NS*HIDC*NM*2;      // 262144
  float2* Xg   = (float2*)(ws + off); off += (size_t)NS*HIDC*NM*2;      // 262144
  float4* u1wT = (float4*)(ws + off); off += (size_t)524288*4;          // 2097152
  float2* vwT  = (float2*)(ws + off); off += (size_t)65536*2;           // 131072
  float2* OS   = (float2*)(ws + off); off += (size_t)NS*IN_CH*NM*2;     // 32768

  prep_kernel<<<2369, 256, 0, stream>>>(qwr, qwi, kwr, kwi, vwr, vwi, u1wr, u1wi,
                                        Etab, G2, Gdc, vwT, u1wT);
  fwd_dft_kernel<<<NS*IN_CH, 512, 0, stream>>>(v, Etab, Vf);
  attn_kernel<<<512, 256, 0, stream>>>(Vf, G2, Gdc, A);
  uspec_kernel<<<512, 256, 0, stream>>>(Vf, vwT, A, Uf);
  mix1_kernel<<<256, 256, 0, stream>>>(Uf, u1wT, s1w, U1f, S1f);
  xg_kernel<<<1024, 512, 0, stream>>>(Etab, U1f, Xg);
  final_spec_kernel<<<NS, 256, 0, stream>>>(S1f, Xg, u2wr, u2wi, s1b, s2w, OS);
  final_kernel<<<NS*8, 512, 0, stream>>>(Etab, U1f, OS, s1b, s2w, s2b, out);
}

// Round 11
// 196.452 us; speedup vs baseline: 1.2237x; 1.0208x over previous
//
#include <hip/hip_runtime.h>
#include <math.h>

#define HEADS 8
#define HIDC  32
#define MODES 8
#define IN_CH 4
#define SEQ   32
#define NS    64      // B*SEQ samples
#define HD    256     // HEADS*HIDC
#define NM    64      // MODES*MODES
#define NPIX  4096    // 64*64

__device__ __forceinline__ float2 f2(float a, float b){ return make_float2(a,b); }

// (cos,sin)(2*pi*k/64), k=0..63 — exact compile-time literals.
__device__ __constant__ float2 c_tw[64] = {
  { 1.000000000000000f, 0.000000000000000f}, { 0.995184726672197f, 0.098017140329561f},
  { 0.980785280403230f, 0.195090322016128f}, { 0.956940335732209f, 0.290284677254462f},
  { 0.923879532511287f, 0.382683432365090f}, { 0.881921264348355f, 0.471396736825998f},
  { 0.831469612302545f, 0.555570233019602f}, { 0.773010453362737f, 0.634393284163645f},
  { 0.707106781186548f, 0.707106781186548f}, { 0.634393284163645f, 0.773010453362737f},
  { 0.555570233019602f, 0.831469612302545f}, { 0.471396736825998f, 0.881921264348355f},
  { 0.382683432365090f, 0.923879532511287f}, { 0.290284677254462f, 0.956940335732209f},
  { 0.195090322016128f, 0.980785280403230f}, { 0.098017140329561f, 0.995184726672197f},
  { 0.000000000000000f, 1.000000000000000f}, {-0.098017140329561f, 0.995184726672197f},
  {-0.195090322016128f, 0.980785280403230f}, {-0.290284677254462f, 0.956940335732209f},
  {-0.382683432365090f, 0.923879532511287f}, {-0.471396736825998f, 0.881921264348355f},
  {-0.555570233019602f, 0.831469612302545f}, {-0.634393284163645f, 0.773010453362737f},
  {-0.707106781186548f, 0.707106781186548f}, {-0.773010453362737f, 0.634393284163645f},
  {-0.831469612302545f, 0.555570233019602f}, {-0.881921264348355f, 0.471396736825998f},
  {-0.923879532511287f, 0.382683432365090f}, {-0.956940335732209f, 0.290284677254462f},
  {-0.980785280403230f, 0.195090322016128f}, {-0.995184726672197f, 0.098017140329561f},
  {-1.000000000000000f, 0.000000000000000f}, {-0.995184726672197f,-0.098017140329561f},
  {-0.980785280403230f,-0.195090322016128f}, {-0.956940335732209f,-0.290284677254462f},
  {-0.923879532511287f,-0.382683432365090f}, {-0.881921264348355f,-0.471396736825998f},
  {-0.831469612302545f,-0.555570233019602f}, {-0.773010453362737f,-0.634393284163645f},
  {-0.707106781186548f,-0.707106781186548f}, {-0.634393284163645f,-0.773010453362737f},
  {-0.555570233019602f,-0.831469612302545f}, {-0.471396736825998f,-0.881921264348355f},
  {-0.382683432365090f,-0.923879532511287f}, {-0.290284677254462f,-0.956940335732209f},
  {-0.195090322016128f,-0.980785280403230f}, {-0.098017140329561f,-0.995184726672197f},
  { 0.000000000000000f,-1.000000000000000f}, { 0.098017140329561f,-0.995184726672197f},
  { 0.195090322016128f,-0.980785280403230f}, { 0.290284677254462f,-0.956940335732209f},
  { 0.382683432365090f,-0.923879532511287f}, { 0.471396736825998f,-0.881921264348355f},
  { 0.555570233019602f,-0.831469612302545f}, { 0.634393284163645f,-0.773010453362737f},
  { 0.707106781186548f,-0.707106781186548f}, { 0.773010453362737f,-0.634393284163645f},
  { 0.831469612302545f,-0.555570233019602f}, { 0.881921264348355f,-0.471396736825998f},
  { 0.923879532511287f,-0.382683432365090f}, { 0.956940335732209f,-0.290284677254462f},
  { 0.980785280403230f,-0.195090322016128f}, { 0.995184726672197f,-0.098017140329561f}
};

// ---------------------------------------------------------------------------
// K-prep: bid 0..63 gram (m=bid); 64..319 vwT; 320..2367 u1wT.
// ---------------------------------------------------------------------------
__global__ __launch_bounds__(256) void prep_kernel(const float* __restrict__ qwr, const float* __restrict__ qwi,
                                                   const float* __restrict__ kwr, const float* __restrict__ kwi,
                                                   const float* __restrict__ vwr, const float* __restrict__ vwi,
                                                   const float* __restrict__ u1wr, const float* __restrict__ u1wi,
                                                   float2* __restrict__ G2, float* __restrict__ Gdc,
                                                   float2* __restrict__ vwT,
                                                   float4* __restrict__ u1wT){
  int bid = blockIdx.x, tid = threadIdx.x;
  if (bid < 64){
    int m = bid;
    __shared__ float qsr[4][257], qsi[4][257], ksr[4][257], ksi[4][257];
    for (int k = tid; k < 1024; k += 256){
      int i = k >> 8, c = k & 255;
      size_t a = ((size_t)(i*256 + c))*64 + m;
      qsr[i][c] = qwr[a]; qsi[i][c] = qwi[a];
      ksr[i][c] = kwr[a]; ksi[i][c] = kwi[a];
    }
    __syncthreads();
    int kx = m & 7, ky = m >> 3;
    float w = (kx >= 1) ? 2.0f : ((ky >= 1) ? 0.5f : 0.0f);
    for (int e = tid; e < 1024; e += 256){
      int P = e >> 7, T = (e >> 4) & 7, i = (e >> 2) & 3, j = e & 3;
      float grr=0.f, gri=0.f, gir=0.f, gii=0.f;
      for (int d = 0; d < 32; ++d){
        float ar = qsr[i][P*32+d], ai = qsi[i][P*32+d];
        float br = ksr[j][T*32+d], bi = ksi[j][T*32+d];
        grr += ar*br; gri += ar*bi; gir += ai*br; gii += ai*bi;
      }
      G2[(size_t)(((m*8+P)*4+i)*4+j)*8 + T] = f2(w*(grr+gii), w*(gir-gri));
      if (m == 0){
        int o = ((P*4+i)*4+j)*8 + T;
        Gdc[o] = grr; Gdc[1024+o] = gri; Gdc[2048+o] = gir; Gdc[3072+o] = gii;
      }
    }
    return;
  }
  if (bid < 320){
    int t = (bid - 64)*256 + tid;     // 65536 = (i*256+c)*64 + m
    int m = t & 63, r = t >> 6, i = r >> 8, c = r & 255;
    vwT[((size_t)m*256 + c)*4 + i] = f2(vwr[t], vwi[t]);
    return;
  }
  {
    int t = (bid - 320)*256 + tid;    // 524288 = (c*32+o1)*64 + m
    int m = t & 63, r = t >> 6, c = r >> 5, o1 = r & 31;
    float pr = ((m & 7)==0 && m) ? 0.5f : 1.0f;
    float pi = m ? pr : 0.0f;
    float wr = u1wr[t], wi = u1wi[t];
    u1wT[((size_t)m*256 + c)*32 + o1] = make_float4(pr*wr, pi*wi, pr*wi, pi*wr);
  }
}

// ---------------------------------------------------------------------------
// K1: partial forward DFT of v: per field [64][64] -> 8x8 low modes.
// ---------------------------------------------------------------------------
__global__ __launch_bounds__(512) void fwd_dft_kernel(const float* __restrict__ src,
                                                      float2* __restrict__ dst){
  int f = blockIdx.x, tid = threadIdx.x;
  __shared__ float  s_fld[64*68];
  __shared__ float2 s_e[64][8];
  __shared__ float2 s_a1[64][8];
  { int a = tid >> 3, b = tid & 7; s_e[a][b] = c_tw[(a*b) & 63]; }
  const float4* f4 = (const float4*)(src + (size_t)f*NPIX);
  for (int k = tid; k < 1024; k += 512){
    float4 v = f4[k];
    int y = k >> 4, x4 = (k & 15)*4;
    float* row = &s_fld[y*68 + x4];
    row[0]=v.x; row[1]=v.y; row[2]=v.z; row[3]=v.w;
  }
  __syncthreads();
  {
    int y = tid >> 3, kx = tid & 7;
    const float4* row = (const float4*)&s_fld[y*68];
    float sr0=0.f, si0=0.f, sr1=0.f, si1=0.f;
    for (int x4 = 0; x4 < 8; ++x4){
      float4 v = row[x4];
      int xb = x4*4;
      float2 c0 = s_e[xb+0][kx], c1 = s_e[xb+1][kx];
      float2 c2 = s_e[xb+2][kx], c3 = s_e[xb+3][kx];
      sr0 += v.x*c0.x + v.y*c1.x + v.z*c2.x + v.w*c3.x;
      si0 -= v.x*c0.y + v.y*c1.y + v.z*c2.y + v.w*c3.y;
    }
    for (int x4 = 8; x4 < 16; ++x4){
      float4 v = row[x4];
      int xb = x4*4;
      float2 c0 = s_e[xb+0][kx], c1 = s_e[xb+1][kx];
      float2 c2 = s_e[xb+2][kx], c3 = s_e[xb+3][kx];
      sr1 += v.x*c0.x + v.y*c1.x + v.z*c2.x + v.w*c3.x;
      si1 -= v.x*c0.y + v.y*c1.y + v.z*c2.y + v.w*c3.y;
    }
    s_a1[y][kx] = f2(sr0+sr1, si0+si1);
  }
  __syncthreads();
  if (tid < 64){
    int ky = tid >> 3, kx = tid & 7;
    float sr0=0.f, si0=0.f, sr1=0.f, si1=0.f;
    for (int y = 0; y < 32; ++y){
      float2 a = s_a1[y][kx];
      float2 cs = s_e[y][ky];
      sr0 += a.x*cs.x + a.y*cs.y;
      si0 += a.y*cs.x - a.x*cs.y;
    }
    for (int y = 32; y < 64; ++y){
      float2 a = s_a1[y][kx];
      float2 cs = s_e[y][ky];
      sr1 += a.x*cs.x + a.y*cs.y;
      si1 += a.y*cs.x - a.x*cs.y;
    }
    dst[(size_t)f*NM + tid] = f2(sr0+sr1, si0+si1);
  }
}

// ---------------------------------------------------------------------------
// K3: attention logits via Parseval + softmax -> A.
// ---------------------------------------------------------------------------
__global__ __launch_bounds__(256) void attn_kernel(const float2* __restrict__ Vf,
                                                   const float2* __restrict__ G2,
                                                   const float* __restrict__ Gdc,
                                                   float* __restrict__ A){
  int bx = blockIdx.x;                 // (b<<8)|(hh<<5)|s
  int s = bx & 31;
  int base = ((bx >> 8) * 32) + (((bx >> 5) & 7) * 4);
  int tid = threadIdx.x;
  int t = tid & 31, mc = tid >> 5;
  __shared__ float2 s_vf[4][IN_CH][64];
  __shared__ float  s_part[8][33];
  for (int k = tid; k < 4*IN_CH*64; k += 256){
    int m = k & 63, c = (k>>6)&3, smp = k>>8;
    s_vf[smp][c][m] = Vf[((size_t)(base+smp)*IN_CH + c)*NM + m];
  }
  __syncthreads();
  int sg = s >> 3, P = s & 7;
  int tg = t >> 3, T = t & 7;
  float acc = 0.f;
  for (int mm = 0; mm < 8; ++mm){
    int m = mc*8 + mm;
    const float2* g = G2 + (size_t)((m*8+P)*16)*8 + T;
    float sub = 0.f;
    for (int i = 0; i < 4; ++i){
      float2 a = s_vf[sg][i][m];
      for (int j = 0; j < 4; ++j){
        float2 b = s_vf[tg][j][m];
        float zr = a.x*b.x + a.y*b.y;
        float zi = a.y*b.x - a.x*b.y;
        float2 gv = g[(size_t)(i*4+j)*8];
        sub += zr*gv.x - zi*gv.y;
      }
    }
    acc += sub;
  }
  if (mc == 0){
    float sub = 0.f;
    for (int i = 0; i < 4; ++i){
      float2 a = s_vf[sg][i][0];
      for (int j = 0; j < 4; ++j){
        float2 b = s_vf[tg][j][0];
        int o = ((P*4+i)*4+j)*8 + T;
        sub += a.x*b.x*Gdc[o] - a.x*b.y*Gdc[1024+o]
             - a.y*b.x*Gdc[2048+o] + a.y*b.y*Gdc[3072+o];
      }
    }
    acc += sub;
  }
  s_part[mc][t] = acc;
  __syncthreads();
  if (tid < 32){
    float l2 = 0.f;
    for (int k = 0; k < 8; ++k) l2 += s_part[k][tid];
    l2 *= 0.5f / (4096.0f * 4096.0f);
    float mx = l2;
    for (int off = 16; off; off >>= 1) mx = fmaxf(mx, __shfl_xor(mx, off, 32));
    float e = expf(l2 - mx);
    float sm = e;
    for (int off = 16; off; off >>= 1) sm += __shfl_xor(sm, off, 32);
    A[(size_t)bx*32 + tid] = e / sm;
  }
}

// ---------------------------------------------------------------------------
// K4: fused vconv + attention-apply. Block per (b,hh,m-pair). Uf[n][m][c].
// ---------------------------------------------------------------------------
__global__ __launch_bounds__(256) void uspec_kernel(const float2* __restrict__ Vf,
                                                    const float2* __restrict__ vwT,
                                                    const float* __restrict__ A,
                                                    float2* __restrict__ Uf){
  int bid = blockIdx.x;                // b*256 + hh*32 + mg
  int mg = bid & 31, hh = (bid >> 5) & 7, b = bid >> 8;
  int m0 = mg*2;
  int nbase = b*32 + hh*4;
  int tid = threadIdx.x;
  __shared__ float2 s_vw[4][2][256];   // [i][mm][c]
  __shared__ float2 s_vv[4][2][256];   // [smp][mm][c]
  __shared__ float  s_A[32][33];
  __shared__ float2 s_vf[4][4][2];
  for (int k = tid; k < 2048; k += 256){
    int mm = k >> 10, c = (k >> 2) & 255, i = k & 3;
    s_vw[i][mm][c] = vwT[(size_t)m0*1024 + k];
  }
  for (int k = tid; k < 1024; k += 256)
    s_A[k>>5][k&31] = A[(size_t)((b*8+hh)*32 + (k>>5))*32 + (k&31)];
  if (tid < 32){
    int smp = tid >> 3, i = (tid >> 1) & 3, mm = tid & 1;
    s_vf[smp][i][mm] = Vf[((size_t)(nbase+smp)*4 + i)*64 + m0 + mm];
  }
  __syncthreads();
  for (int k = tid; k < 2048; k += 256){
    int smp = k >> 9, mm = (k >> 8) & 1, c = k & 255;
    float sr = 0.f, si = 0.f;
    for (int i = 0; i < 4; ++i){
      float2 v = s_vf[smp][i][mm];
      float2 w = s_vw[i][mm][c];
      sr += v.x*w.x - v.y*w.y;
      si += v.x*w.y + v.y*w.x;
    }
    s_vv[smp][mm][c] = f2(sr, si);
  }
  __syncthreads();
  int sg = tid >> 5, d = tid & 31;
  float2 acc[4][2];
  for (int ss = 0; ss < 4; ++ss)
    for (int mm = 0; mm < 2; ++mm) acc[ss][mm] = f2(0.f, 0.f);
  for (int tt = 0; tt < 32; ++tt){
    int tg = tt >> 3, c = (tt & 7)*32 + d;
    float a0 = s_A[sg*4+0][tt], a1 = s_A[sg*4+1][tt];
    float a2 = s_A[sg*4+2][tt], a3 = s_A[sg*4+3][tt];
    for (int mm = 0; mm < 2; ++mm){
      float2 v = s_vv[tg][mm][c];
      acc[0][mm].x += a0*v.x; acc[0][mm].y += a0*v.y;
      acc[1][mm].x += a1*v.x; acc[1][mm].y += a1*v.y;
      acc[2][mm].x += a2*v.x; acc[2][mm].y += a2*v.y;
      acc[3][mm].x += a3*v.x; acc[3][mm].y += a3*v.y;
    }
  }
  for (int ss = 0; ss < 4; ++ss){
    int n = b*32 + sg*4 + ss;
    for (int mm = 0; mm < 2; ++mm)
      Uf[((size_t)n*64 + m0 + mm)*256 + hh*32 + d] = acc[ss][mm];
  }
}

// ---------------------------------------------------------------------------
// K5: channel mixes. Block = (8 samples) x (2 modes); 256 thr.
// ---------------------------------------------------------------------------
__global__ __launch_bounds__(256) void mix1_kernel(const float2* __restrict__ Uf,
                                                   const float4* __restrict__ u1wT,
                                                   const float* __restrict__ s1w,
                                                   float2* __restrict__ U1f, float2* __restrict__ S1f){
  int bid = blockIdx.x;                // 256 = ng(8) x mg(32)
  int mg = bid & 31, n0 = (bid >> 5)*8, m0 = mg*2;
  int tid = threadIdx.x;
  __shared__ float2 s_u[8][2][256];    // [s][mm][c] : 32 KB
  __shared__ float  s_w1[32][257];     // padded: o1-major, conflict-free
  for (int it = 0; it < 16; ++it){
    int s = it >> 1, mm = it & 1;
    s_u[s][mm][tid] = Uf[((size_t)(n0+s)*64 + m0 + mm)*256 + tid];
  }
  for (int k = tid; k < 8192; k += 256)
    s_w1[k>>8][k&255] = s1w[k];
  __syncthreads();
  int o1 = tid & 31, mm = (tid >> 5) & 1, sh = tid >> 6;   // sh in 0..3
  int m = m0 + mm, sA = sh*2, sB = sh*2+1;
  const float4* wp = u1wT + (size_t)m*8192 + o1;
  float2 au0 = f2(0,0), au1 = f2(0,0), as0 = f2(0,0), as1 = f2(0,0);
  #pragma unroll 4
  for (int c = 0; c < 256; ++c){
    float4 w = wp[(size_t)c*32];
    float sw = s_w1[o1][c];
    float2 uA = s_u[sA][mm][c];
    float2 uB = s_u[sB][mm][c];
    au0.x += uA.x*w.x - uA.y*w.y;  au0.y += uA.x*w.z + uA.y*w.w;
    au1.x += uB.x*w.x - uB.y*w.y;  au1.y += uB.x*w.z + uB.y*w.w;
    as0.x += uA.x*sw;  as0.y += uA.y*sw;
    as1.x += uB.x*sw;  as1.y += uB.y*sw;
  }
  size_t obA = ((size_t)(n0+sA)*32 + o1)*64 + m;
  size_t obB = ((size_t)(n0+sB)*32 + o1)*64 + m;
  U1f[obA] = au0; S1f[obA] = as0;
  U1f[obB] = au1; S1f[obB] = as1;
}

// ---------------------------------------------------------------------------
// K6: Xg = DFT8x8( gelu( irfft(U1f) ) ); ALSO stores the gelu field g to
// global (coalesced, fire-and-forget) so final_kernel reads instead of
// recomputing. 2 fields/block, 512 threads.
// ---------------------------------------------------------------------------
__global__ __launch_bounds__(512) void xg_kernel(const float2* __restrict__ U1f,
                                                 float2* __restrict__ Xg,
                                                 float* __restrict__ g){
  int f0 = blockIdx.x*2, tid = threadIdx.x;
  __shared__ float2 s_e[64][8];
  __shared__ float2 s_eT[8][64];
  __shared__ float2 s_gu[2][64];
  __shared__ float2 s_tu[2][64][8];    // aliased as s_a1 after phase B
  __shared__ float  s_fld[2][64*68];
  { int a = tid >> 3, b = tid & 7; float2 v = c_tw[(a*b) & 63]; s_e[a][b] = v; s_eT[b][a] = v; }
  if (tid < 128) ((float2*)s_gu)[tid] = U1f[(size_t)f0*NM + tid];
  __syncthreads();
  for (int o = tid; o < 1024; o += 512){
    int fl = o >> 9, r = o & 511, y = r >> 3, kx = r & 7;
    float wf = (kx ? 2.0f : 1.0f) * (1.0f/4096.0f);
    float a0=0.f, b0=0.f, a1=0.f, b1=0.f;
    for (int ky = 0; ky < 4; ++ky){
      float2 cs = s_e[y][ky];
      float2 gu = s_gu[fl][ky*8+kx];
      a0 += gu.x*cs.x - gu.y*cs.y;
      b0 += gu.x*cs.y + gu.y*cs.x;
    }
    for (int ky = 4; ky < 8; ++ky){
      float2 cs = s_e[y][ky];
      float2 gu = s_gu[fl][ky*8+kx];
      a1 += gu.x*cs.x - gu.y*cs.y;
      b1 += gu.x*cs.y + gu.y*cs.x;
    }
    s_tu[fl][y][kx] = f2((a0+a1)*wf, (b0+b1)*wf);
  }
  __syncthreads();
  int xx = tid & 63;
  float2 ce[8];
  #pragma unroll
  for (int k = 0; k < 8; ++k) ce[k] = s_eT[k][xx];
  float* g0p = g + (size_t)f0*NPIX;
  for (int i = 0; i < 8; ++i){
    int p = i*512 + tid, y = p >> 6;   // wave-uniform y
    const float4* tp0 = (const float4*)&s_tu[0][y][0];
    const float4* tp1 = (const float4*)&s_tu[1][y][0];
    float4 a0=tp0[0], a1=tp0[1], a2=tp0[2], a3=tp0[3];
    float4 b0=tp1[0], b1=tp1[1], b2=tp1[2], b3=tp1[3];
    float h0 = a0.x*ce[0].x - a0.y*ce[0].y + a0.z*ce[1].x - a0.w*ce[1].y
             + a1.x*ce[2].x - a1.y*ce[2].y + a1.z*ce[3].x - a1.w*ce[3].y;
    float h1 = a2.x*ce[4].x - a2.y*ce[4].y + a2.z*ce[5].x - a2.w*ce[5].y
             + a3.x*ce[6].x - a3.y*ce[6].y + a3.z*ce[7].x - a3.w*ce[7].y;
    float k0 = b0.x*ce[0].x - b0.y*ce[0].y + b0.z*ce[1].x - b0.w*ce[1].y
             + b1.x*ce[2].x - b1.y*ce[2].y + b1.z*ce[3].x - b1.w*ce[3].y;
    float k1 = b2.x*ce[4].x - b2.y*ce[4].y + b2.z*ce[5].x - b2.w*ce[5].y
             + b3.x*ce[6].x - b3.y*ce[6].y + b3.z*ce[7].x - b3.w*ce[7].y;
    float v0 = h0 + h1, v1 = k0 + k1;
    float ga = 0.5f * v0 * (1.0f + erff(v0 * 0.70710678f));
    float gb = 0.5f * v1 * (1.0f + erff(v1 * 0.70710678f));
    s_fld[0][y*68 + xx] = ga;
    s_fld[1][y*68 + xx] = gb;
    g0p[p] = ga;
    g0p[NPIX + p] = gb;
  }
  __syncthreads();
  float2 (*s_a1)[64][8] = s_tu;
  for (int o = tid; o < 1024; o += 512){
    int fl = o >> 9, r = o & 511, y = r >> 3, kx = r & 7;
    const float4* row = (const float4*)&s_fld[fl][y*68];
    float sr0=0.f, si0=0.f, sr1=0.f, si1=0.f;
    for (int x4 = 0; x4 < 8; ++x4){
      float4 v = row[x4];
      int xb = x4*4;
      float2 c0 = s_e[xb+0][kx], c1 = s_e[xb+1][kx];
      float2 c2 = s_e[xb+2][kx], c3 = s_e[xb+3][kx];
      sr0 += v.x*c0.x + v.y*c1.x + v.z*c2.x + v.w*c3.x;
      si0 -= v.x*c0.y + v.y*c1.y + v.z*c2.y + v.w*c3.y;
    }
    for (int x4 = 8; x4 < 16; ++x4){
      float4 v = row[x4];
      int xb = x4*4;
      float2 c0 = s_e[xb+0][kx], c1 = s_e[xb+1][kx];
      float2 c2 = s_e[xb+2][kx], c3 = s_e[xb+3][kx];
      sr1 += v.x*c0.x + v.y*c1.x + v.z*c2.x + v.w*c3.x;
      si1 -= v.x*c0.y + v.y*c1.y + v.z*c2.y + v.w*c3.y;
    }
    s_a1[fl][y][kx] = f2(sr0+sr1, si0+si1);
  }
  __syncthreads();
  if (tid < 128){
    int fl = tid >> 6, t6 = tid & 63;
    int ky = t6 >> 3, kx = t6 & 7;
    float sr0=0.f, si0=0.f, sr1=0.f, si1=0.f;
    for (int y = 0; y < 32; ++y){
      float2 a = s_a1[fl][y][kx];
      float2 cs = s_e[y][ky];
      sr0 += a.x*cs.x + a.y*cs.y;
      si0 += a.y*cs.x - a.x*cs.y;
    }
    for (int y = 32; y < 64; ++y){
      float2 a = s_a1[fl][y][kx];
      float2 cs = s_e[y][ky];
      sr1 += a.x*cs.x + a.y*cs.y;
      si1 += a.y*cs.x - a.x*cs.y;
    }
    Xg[(size_t)(f0+fl)*NM + t6] = f2(sr0+sr1, si0+si1);
  }
}

// ---------------------------------------------------------------------------
// K7a: per-sample output spectrum (once per sample).
// ---------------------------------------------------------------------------
__global__ __launch_bounds__(256) void final_spec_kernel(const float2* __restrict__ S1f,
                                                         const float2* __restrict__ Xg,
                                                         const float* __restrict__ u2wr, const float* __restrict__ u2wi,
                                                         const float* __restrict__ s1b,
                                                         const float* __restrict__ s2w,
                                                         float2* __restrict__ OS){
  int n = blockIdx.x, tid = threadIdx.x;
  __shared__ float s_w2[128], s_s1b[32];
  if (tid < 128) s_w2[tid] = s2w[tid];
  else if (tid < 160) s_s1b[tid-128] = s1b[tid-128];
  __syncthreads();
  int o2 = tid >> 6, m = tid & 63;
  float prm = ((m & 7)==0 && m) ? 0.5f : 1.0f;
  float pim = m ? prm : 0.0f;
  float dc = (m == 0) ? 4096.0f : 0.0f;
  float cr = 0.f, ci = 0.f;
  for (int o1 = 0; o1 < 32; ++o1){
    float2 xg = Xg[((size_t)n*32 + o1)*NM + m];
    float2 sf = S1f[((size_t)n*32 + o1)*NM + m];
    float Xr = xg.x + sf.x*prm + dc*s_s1b[o1];
    float Xi = xg.y + sf.y*pim;
    size_t wb = ((size_t)(o1*IN_CH + o2))*NM + m;
    float wr = u2wr[wb], wi = u2wi[wb];
    float sw = s_w2[o2*32 + o1];
    cr += Xr*wr - Xi*wi + sw*sf.x;
    ci += Xr*wi + Xi*wr + sw*sf.y;
  }
  OS[((size_t)n*IN_CH + o2)*NM + m] = f2(cr, ci);
}

// ---------------------------------------------------------------------------
// K7b: thin pixel kernel: out = irfft(OS) + s2 x g(loaded) + s2*s1b + b2.
// 8-row tiles, 512 threads, 1 px/thread. ~13 KB LDS.
// ---------------------------------------------------------------------------
__global__ __launch_bounds__(512) void final_kernel(const float* __restrict__ g,
                                                    const float2* __restrict__ OS,
                                                    const float* __restrict__ s1b,
                                                    const float* __restrict__ s2w, const float* __restrict__ s2b,
                                                    float* __restrict__ out){
  int n = blockIdx.x >> 3, tile = blockIdx.x & 7, y0 = tile*8;
  int tid = threadIdx.x;
  __shared__ float2 s_e[64][8];
  __shared__ float2 s_eT[8][64];
  __shared__ float2 s_os[4][64];
  __shared__ float2 s_tmp[4][8][8];
  __shared__ float  s_w2[128], s_s1b[32], s_b2[4];
  { int a = tid >> 3, b = tid & 7; float2 v = c_tw[(a*b) & 63]; s_e[a][b] = v; s_eT[b][a] = v; }
  if (tid < 256) ((float2*)s_os)[tid] = OS[(size_t)n*256 + tid];
  else if (tid < 384) s_w2[tid-256] = s2w[tid-256];
  else if (tid < 416) s_s1b[tid-384] = s1b[tid-384];
  else if (tid < 420) s_b2[tid-416] = s2b[tid-416];
  __syncthreads();
  // OS y-transform for this tile's 8 rows
  if (tid < 256){
    int o2 = tid >> 6, yy = (tid >> 3) & 7, kx = tid & 7;
    int y = y0 + yy;
    float wf = (kx ? 2.0f : 1.0f) * (1.0f/4096.0f);
    float tr=0.f, ti=0.f;
    for (int ky = 0; ky < 8; ++ky){
      float2 cs = s_e[y][ky];
      float2 gv = s_os[o2][ky*8+kx];
      tr += gv.x*cs.x - gv.y*cs.y;
      ti += gv.x*cs.y + gv.y*cs.x;
    }
    s_tmp[o2][yy][kx] = f2(tr*wf, ti*wf);
  }
  __syncthreads();
  // pixels
  int yy = tid >> 6, xx = tid & 63;
  int p = (y0 + yy)*64 + xx;
  float2 ce[8];
  #pragma unroll
  for (int k = 0; k < 8; ++k) ce[k] = s_eT[k][xx];
  float a0 = s_b2[0], a1 = s_b2[1], a2 = s_b2[2], a3 = s_b2[3];
  for (int c = 0; c < 32; ++c){
    float b = s_s1b[c];
    a0 += s_w2[c]*b; a1 += s_w2[32+c]*b; a2 += s_w2[64+c]*b; a3 += s_w2[96+c]*b;
  }
  const float* gp = g + (size_t)n*HIDC*NPIX + p;
  #pragma unroll 8
  for (int c = 0; c < 32; ++c){
    float gv = gp[(size_t)c*NPIX];
    a0 += s_w2[c]*gv; a1 += s_w2[32+c]*gv; a2 += s_w2[64+c]*gv; a3 += s_w2[96+c]*gv;
  }
  float sp[4];
  #pragma unroll
  for (int o2 = 0; o2 < 4; ++o2){
    const float4* tp = (const float4*)&s_tmp[o2][yy][0];
    float4 t0 = tp[0], t1 = tp[1], t2 = tp[2], t3 = tp[3];
    float h0 = t0.x*ce[0].x - t0.y*ce[0].y + t0.z*ce[1].x - t0.w*ce[1].y
             + t1.x*ce[2].x - t1.y*ce[2].y + t1.z*ce[3].x - t1.w*ce[3].y;
    float h1 = t2.x*ce[4].x - t2.y*ce[4].y + t2.z*ce[5].x - t2.w*ce[5].y
             + t3.x*ce[6].x - t3.y*ce[6].y + t3.z*ce[7].x - t3.w*ce[7].y;
    sp[o2] = h0 + h1;
  }
  float* ob = out + (size_t)n*IN_CH*NPIX;
  ob[p]          = a0 + sp[0];
  ob[NPIX + p]   = a1 + sp[1];
  ob[2*NPIX + p] = a2 + sp[2];
  ob[3*NPIX + p] = a3 + sp[3];
}

extern "C" void kernel_launch(void* const* d_in, const int* in_sizes, int n_in,
                              void* d_out, int out_size, void* d_ws, size_t ws_size,
                              hipStream_t stream) {
  (void)in_sizes; (void)n_in; (void)out_size; (void)ws_size;
  const float* v    = (const float*)d_in[0];
  const float* qwr  = (const float*)d_in[1];
  const float* qwi  = (const float*)d_in[2];
  const float* kwr  = (const float*)d_in[3];
  const float* kwi  = (const float*)d_in[4];
  const float* vwr  = (const float*)d_in[5];
  const float* vwi  = (const float*)d_in[6];
  const float* u1wr = (const float*)d_in[7];
  const float* u1wi = (const float*)d_in[8];
  const float* u2wr = (const float*)d_in[9];
  const float* u2wi = (const float*)d_in[10];
  const float* s1w  = (const float*)d_in[11];
  const float* s1b  = (const float*)d_in[12];
  const float* s2w  = (const float*)d_in[13];
  const float* s2b  = (const float*)d_in[14];
  float* out = (float*)d_out;

  float* ws = (float*)d_ws;
  size_t off = 0;
  float2* Vf   = (float2*)(ws + off); off += (size_t)NS*IN_CH*NM*2;     // 32768
  float2* G2   = (float2*)(ws + off); off += (size_t)65536*2;           // 131072
  float*  Gdc  =          (ws + off); off += 4096;
  float*  A    =          (ws + off); off += 16384;
  float2* Uf   = (float2*)(ws + off); off += (size_t)NS*NM*HD*2;        // 2097152
  float2* U1f  = (float2*)(ws + off); off += (size_t)NS*HIDC*NM*2;      // 262144
  float2* S1f  = (float2*)(ws + off); off += (size_t)NS*HIDC*NM*2;      // 262144
  float2* Xg   = (float2*)(ws + off); off += (size_t)NS*HIDC*NM*2;      // 262144
  float4* u1wT = (float4*)(ws + off); off += (size_t)524288*4;          // 2097152
  float2* vwT  = (float2*)(ws + off); off += (size_t)65536*2;           // 131072
  float2* OS   = (float2*)(ws + off); off += (size_t)NS*IN_CH*NM*2;     // 32768
  float*  gfld =          (ws + off); off += (size_t)NS*HIDC*NPIX;      // 8388608

  prep_kernel<<<2368, 256, 0, stream>>>(qwr, qwi, kwr, kwi, vwr, vwi, u1wr, u1wi,
                                        G2, Gdc, vwT, u1wT);
  fwd_dft_kernel<<<NS*IN_CH, 512, 0, stream>>>(v, Vf);
  attn_kernel<<<512, 256, 0, stream>>>(Vf, G2, Gdc, A);
  uspec_kernel<<<512, 256, 0, stream>>>(Vf, vwT, A, Uf);
  mix1_kernel<<<256, 256, 0, stream>>>(Uf, u1wT, s1w, U1f, S1f);
  xg_kernel<<<1024, 512, 0, stream>>>(U1f, Xg, gfld);
  final_spec_kernel<<<NS, 256, 0, stream>>>(S1f, Xg, u2wr, u2wi, s1b, s2w, OS);
  final_kernel<<<NS*8, 512, 0, stream>>>(gfld, OS, s1b, s2w, s2b, out);
}

// Round 13
// 192.418 us; speedup vs baseline: 1.2494x; 1.0210x over previous
//
#include <hip/hip_runtime.h>
#include <math.h>

#define HEADS 8
#define HIDC  32
#define MODES 8
#define IN_CH 4
#define SEQ   32
#define NS    64      // B*SEQ samples
#define HD    256     // HEADS*HIDC
#define NM    64      // MODES*MODES
#define NPIX  4096    // 64*64

__device__ __forceinline__ float2 f2(float a, float b){ return make_float2(a,b); }

// (cos,sin)(2*pi*k/64), k=0..63 — exact compile-time literals.
__device__ __constant__ float2 c_tw[64] = {
  { 1.000000000000000f, 0.000000000000000f}, { 0.995184726672197f, 0.098017140329561f},
  { 0.980785280403230f, 0.195090322016128f}, { 0.956940335732209f, 0.290284677254462f},
  { 0.923879532511287f, 0.382683432365090f}, { 0.881921264348355f, 0.471396736825998f},
  { 0.831469612302545f, 0.555570233019602f}, { 0.773010453362737f, 0.634393284163645f},
  { 0.707106781186548f, 0.707106781186548f}, { 0.634393284163645f, 0.773010453362737f},
  { 0.555570233019602f, 0.831469612302545f}, { 0.471396736825998f, 0.881921264348355f},
  { 0.382683432365090f, 0.923879532511287f}, { 0.290284677254462f, 0.956940335732209f},
  { 0.195090322016128f, 0.980785280403230f}, { 0.098017140329561f, 0.995184726672197f},
  { 0.000000000000000f, 1.000000000000000f}, {-0.098017140329561f, 0.995184726672197f},
  {-0.195090322016128f, 0.980785280403230f}, {-0.290284677254462f, 0.956940335732209f},
  {-0.382683432365090f, 0.923879532511287f}, {-0.471396736825998f, 0.881921264348355f},
  {-0.555570233019602f, 0.831469612302545f}, {-0.634393284163645f, 0.773010453362737f},
  {-0.707106781186548f, 0.707106781186548f}, {-0.773010453362737f, 0.634393284163645f},
  {-0.831469612302545f, 0.555570233019602f}, {-0.881921264348355f, 0.471396736825998f},
  {-0.923879532511287f, 0.382683432365090f}, {-0.956940335732209f, 0.290284677254462f},
  {-0.980785280403230f, 0.195090322016128f}, {-0.995184726672197f, 0.098017140329561f},
  {-1.000000000000000f, 0.000000000000000f}, {-0.995184726672197f,-0.098017140329561f},
  {-0.980785280403230f,-0.195090322016128f}, {-0.956940335732209f,-0.290284677254462f},
  {-0.923879532511287f,-0.382683432365090f}, {-0.881921264348355f,-0.471396736825998f},
  {-0.831469612302545f,-0.555570233019602f}, {-0.773010453362737f,-0.634393284163645f},
  {-0.707106781186548f,-0.707106781186548f}, {-0.634393284163645f,-0.773010453362737f},
  {-0.555570233019602f,-0.831469612302545f}, {-0.471396736825998f,-0.881921264348355f},
  {-0.382683432365090f,-0.923879532511287f}, {-0.290284677254462f,-0.956940335732209f},
  {-0.195090322016128f,-0.980785280403230f}, {-0.098017140329561f,-0.995184726672197f},
  { 0.000000000000000f,-1.000000000000000f}, { 0.098017140329561f,-0.995184726672197f},
  { 0.195090322016128f,-0.980785280403230f}, { 0.290284677254462f,-0.956940335732209f},
  { 0.382683432365090f,-0.923879532511287f}, { 0.471396736825998f,-0.881921264348355f},
  { 0.555570233019602f,-0.831469612302545f}, { 0.634393284163645f,-0.773010453362737f},
  { 0.707106781186548f,-0.707106781186548f}, { 0.773010453362737f,-0.634393284163645f},
  { 0.831469612302545f,-0.555570233019602f}, { 0.881921264348355f,-0.471396736825998f},
  { 0.923879532511287f,-0.382683432365090f}, { 0.956940335732209f,-0.290284677254462f},
  { 0.980785280403230f,-0.195090322016128f}, { 0.995184726672197f,-0.098017140329561f}
};

// ---------------------------------------------------------------------------
// K0 (merged prep + v-DFT), 512 threads. Partitions by blockIdx:
//   [0,256)     : fwd DFT of v field f=bid  -> Vf
//   [256,320)   : gram m = bid-256          -> G2, Gdc
//   [320,448)   : vwT transpose
//   [448,1472)  : u1wT transpose (Hermitian projection folded)
// ---------------------------------------------------------------------------
__global__ __launch_bounds__(512) void prep_dft_kernel(const float* __restrict__ v,
                                                       const float* __restrict__ qwr, const float* __restrict__ qwi,
                                                       const float* __restrict__ kwr, const float* __restrict__ kwi,
                                                       const float* __restrict__ vwr, const float* __restrict__ vwi,
                                                       const float* __restrict__ u1wr, const float* __restrict__ u1wi,
                                                       float2* __restrict__ Vf,
                                                       float2* __restrict__ G2, float* __restrict__ Gdc,
                                                       float2* __restrict__ vwT,
                                                       float4* __restrict__ u1wT){
  __shared__ float smem[6400];        // 25.6 KB, unioned across partitions
  int bid = blockIdx.x, tid = threadIdx.x;
  if (bid < 256){
    int f = bid;
    float*  s_fld = smem;                         // 64*68 = 4352
    float2* s_e   = (float2*)(smem + 4352);       // 512 f2
    float2 (*s_a1)[8] = (float2(*)[8])(smem + 5376);
    { int a = tid >> 3, b = tid & 7; s_e[a*8+b] = c_tw[(a*b) & 63]; }
    const float4* f4 = (const float4*)(v + (size_t)f*NPIX);
    for (int k = tid; k < 1024; k += 512){
      float4 vv = f4[k];
      int y = k >> 4, x4 = (k & 15)*4;
      float* row = &s_fld[y*68 + x4];
      row[0]=vv.x; row[1]=vv.y; row[2]=vv.z; row[3]=vv.w;
    }
    __syncthreads();
    {
      int y = tid >> 3, kx = tid & 7;
      const float4* row = (const float4*)&s_fld[y*68];
      float sr0=0.f, si0=0.f, sr1=0.f, si1=0.f;
      for (int x4 = 0; x4 < 8; ++x4){
        float4 vv = row[x4];
        int xb = x4*4;
        float2 c0 = s_e[(xb+0)*8+kx], c1 = s_e[(xb+1)*8+kx];
        float2 c2 = s_e[(xb+2)*8+kx], c3 = s_e[(xb+3)*8+kx];
        sr0 += vv.x*c0.x + vv.y*c1.x + vv.z*c2.x + vv.w*c3.x;
        si0 -= vv.x*c0.y + vv.y*c1.y + vv.z*c2.y + vv.w*c3.y;
      }
      for (int x4 = 8; x4 < 16; ++x4){
        float4 vv = row[x4];
        int xb = x4*4;
        float2 c0 = s_e[(xb+0)*8+kx], c1 = s_e[(xb+1)*8+kx];
        float2 c2 = s_e[(xb+2)*8+kx], c3 = s_e[(xb+3)*8+kx];
        sr1 += vv.x*c0.x + vv.y*c1.x + vv.z*c2.x + vv.w*c3.x;
        si1 -= vv.x*c0.y + vv.y*c1.y + vv.z*c2.y + vv.w*c3.y;
      }
      s_a1[y][kx] = f2(sr0+sr1, si0+si1);
    }
    __syncthreads();
    if (tid < 64){
      int ky = tid >> 3, kx = tid & 7;
      float sr0=0.f, si0=0.f, sr1=0.f, si1=0.f;
      for (int y = 0; y < 32; ++y){
        float2 a = s_a1[y][kx];
        float2 cs = s_e[y*8+ky];
        sr0 += a.x*cs.x + a.y*cs.y;
        si0 += a.y*cs.x - a.x*cs.y;
      }
      for (int y = 32; y < 64; ++y){
        float2 a = s_a1[y][kx];
        float2 cs = s_e[y*8+ky];
        sr1 += a.x*cs.x + a.y*cs.y;
        si1 += a.y*cs.x - a.x*cs.y;
      }
      Vf[(size_t)f*NM + tid] = f2(sr0+sr1, si0+si1);
    }
    return;
  }
  if (bid < 320){
    int m = bid - 256;
    float* qsr = smem;            // [4][257]
    float* qsi = smem + 1028;
    float* ksr = smem + 2056;
    float* ksi = smem + 3084;
    for (int k = tid; k < 1024; k += 512){
      int i = k >> 8, c = k & 255;
      size_t a = ((size_t)(i*256 + c))*64 + m;
      qsr[i*257+c] = qwr[a]; qsi[i*257+c] = qwi[a];
      ksr[i*257+c] = kwr[a]; ksi[i*257+c] = kwi[a];
    }
    __syncthreads();
    int kx = m & 7, ky = m >> 3;
    float w = (kx >= 1) ? 2.0f : ((ky >= 1) ? 0.5f : 0.0f);
    for (int e = tid; e < 1024; e += 512){
      int P = e >> 7, T = (e >> 4) & 7, i = (e >> 2) & 3, j = e & 3;
      float grr=0.f, gri=0.f, gir=0.f, gii=0.f;
      for (int d = 0; d < 32; ++d){
        float ar = qsr[i*257 + P*32+d], ai = qsi[i*257 + P*32+d];
        float br = ksr[j*257 + T*32+d], bi = ksi[j*257 + T*32+d];
        grr += ar*br; gri += ar*bi; gir += ai*br; gii += ai*bi;
      }
      G2[(size_t)(((m*8+P)*4+i)*4+j)*8 + T] = f2(w*(grr+gii), w*(gir-gri));
      if (m == 0){
        int o = ((P*4+i)*4+j)*8 + T;
        Gdc[o] = grr; Gdc[1024+o] = gri; Gdc[2048+o] = gir; Gdc[3072+o] = gii;
      }
    }
    return;
  }
  if (bid < 448){
    int t = (bid - 320)*512 + tid;    // 65536 = (i*256+c)*64 + m
    int m = t & 63, r = t >> 6, i = r >> 8, c = r & 255;
    vwT[((size_t)m*256 + c)*4 + i] = f2(vwr[t], vwi[t]);
    return;
  }
  {
    int t = (bid - 448)*512 + tid;    // 524288 = (c*32+o1)*64 + m
    int m = t & 63, r = t >> 6, c = r >> 5, o1 = r & 31;
    float pr = ((m & 7)==0 && m) ? 0.5f : 1.0f;
    float pi = m ? pr : 0.0f;
    float wr = u1wr[t], wi = u1wi[t];
    u1wT[((size_t)m*256 + c)*32 + o1] = make_float4(pr*wr, pi*wi, pr*wi, pi*wr);
  }
}

// ---------------------------------------------------------------------------
// K3: attention logits via Parseval + softmax -> A.
// ---------------------------------------------------------------------------
__global__ __launch_bounds__(256) void attn_kernel(const float2* __restrict__ Vf,
                                                   const float2* __restrict__ G2,
                                                   const float* __restrict__ Gdc,
                                                   float* __restrict__ A){
  int bx = blockIdx.x;                 // (b<<8)|(hh<<5)|s
  int s = bx & 31;
  int base = ((bx >> 8) * 32) + (((bx >> 5) & 7) * 4);
  int tid = threadIdx.x;
  int t = tid & 31, mc = tid >> 5;
  __shared__ float2 s_vf[4][IN_CH][64];
  __shared__ float  s_part[8][33];
  for (int k = tid; k < 4*IN_CH*64; k += 256){
    int m = k & 63, c = (k>>6)&3, smp = k>>8;
    s_vf[smp][c][m] = Vf[((size_t)(base+smp)*IN_CH + c)*NM + m];
  }
  __syncthreads();
  int sg = s >> 3, P = s & 7;
  int tg = t >> 3, T = t & 7;
  float acc = 0.f;
  for (int mm = 0; mm < 8; ++mm){
    int m = mc*8 + mm;
    const float2* g = G2 + (size_t)((m*8+P)*16)*8 + T;
    float sub = 0.f;
    for (int i = 0; i < 4; ++i){
      float2 a = s_vf[sg][i][m];
      for (int j = 0; j < 4; ++j){
        float2 b = s_vf[tg][j][m];
        float zr = a.x*b.x + a.y*b.y;
        float zi = a.y*b.x - a.x*b.y;
        float2 gv = g[(size_t)(i*4+j)*8];
        sub += zr*gv.x - zi*gv.y;
      }
    }
    acc += sub;
  }
  if (mc == 0){
    float sub = 0.f;
    for (int i = 0; i < 4; ++i){
      float2 a = s_vf[sg][i][0];
      for (int j = 0; j < 4; ++j){
        float2 b = s_vf[tg][j][0];
        int o = ((P*4+i)*4+j)*8 + T;
        sub += a.x*b.x*Gdc[o] - a.x*b.y*Gdc[1024+o]
             - a.y*b.x*Gdc[2048+o] + a.y*b.y*Gdc[3072+o];
      }
    }
    acc += sub;
  }
  s_part[mc][t] = acc;
  __syncthreads();
  if (tid < 32){
    float l2 = 0.f;
    for (int k = 0; k < 8; ++k) l2 += s_part[k][tid];
    l2 *= 0.5f / (4096.0f * 4096.0f);
    float mx = l2;
    for (int off = 16; off; off >>= 1) mx = fmaxf(mx, __shfl_xor(mx, off, 32));
    float e = expf(l2 - mx);
    float sm = e;
    for (int off = 16; off; off >>= 1) sm += __shfl_xor(sm, off, 32);
    A[(size_t)bx*32 + tid] = e / sm;
  }
}

// ---------------------------------------------------------------------------
// K4: fused vconv + attention-apply. Block per (b,hh,m-pair). Uf[n][m][c].
// ---------------------------------------------------------------------------
__global__ __launch_bounds__(256) void uspec_kernel(const float2* __restrict__ Vf,
                                                    const float2* __restrict__ vwT,
                                                    const float* __restrict__ A,
                                                    float2* __restrict__ Uf){
  int bid = blockIdx.x;                // b*256 + hh*32 + mg
  int mg = bid & 31, hh = (bid >> 5) & 7, b = bid >> 8;
  int m0 = mg*2;
  int nbase = b*32 + hh*4;
  int tid = threadIdx.x;
  __shared__ float2 s_vw[4][2][256];   // [i][mm][c]
  __shared__ float2 s_vv[4][2][256];   // [smp][mm][c]
  __shared__ float  s_A[32][33];
  __shared__ float2 s_vf[4][4][2];
  for (int k = tid; k < 2048; k += 256){
    int mm = k >> 10, c = (k >> 2) & 255, i = k & 3;
    s_vw[i][mm][c] = vwT[(size_t)m0*1024 + k];
  }
  for (int k = tid; k < 1024; k += 256)
    s_A[k>>5][k&31] = A[(size_t)((b*8+hh)*32 + (k>>5))*32 + (k&31)];
  if (tid < 32){
    int smp = tid >> 3, i = (tid >> 1) & 3, mm = tid & 1;
    s_vf[smp][i][mm] = Vf[((size_t)(nbase+smp)*4 + i)*64 + m0 + mm];
  }
  __syncthreads();
  for (int k = tid; k < 2048; k += 256){
    int smp = k >> 9, mm = (k >> 8) & 1, c = k & 255;
    float sr = 0.f, si = 0.f;
    for (int i = 0; i < 4; ++i){
      float2 v = s_vf[smp][i][mm];
      float2 w = s_vw[i][mm][c];
      sr += v.x*w.x - v.y*w.y;
      si += v.x*w.y + v.y*w.x;
    }
    s_vv[smp][mm][c] = f2(sr, si);
  }
  __syncthreads();
  int sg = tid >> 5, d = tid & 31;
  float2 acc[4][2];
  for (int ss = 0; ss < 4; ++ss)
    for (int mm = 0; mm < 2; ++mm) acc[ss][mm] = f2(0.f, 0.f);
  for (int tt = 0; tt < 32; ++tt){
    int tg = tt >> 3, c = (tt & 7)*32 + d;
    float a0 = s_A[sg*4+0][tt], a1 = s_A[sg*4+1][tt];
    float a2 = s_A[sg*4+2][tt], a3 = s_A[sg*4+3][tt];
    for (int mm = 0; mm < 2; ++mm){
      float2 v = s_vv[tg][mm][c];
      acc[0][mm].x += a0*v.x; acc[0][mm].y += a0*v.y;
      acc[1][mm].x += a1*v.x; acc[1][mm].y += a1*v.y;
      acc[2][mm].x += a2*v.x; acc[2][mm].y += a2*v.y;
      acc[3][mm].x += a3*v.x; acc[3][mm].y += a3*v.y;
    }
  }
  for (int ss = 0; ss < 4; ++ss){
    int n = b*32 + sg*4 + ss;
    for (int mm = 0; mm < 2; ++mm)
      Uf[((size_t)n*64 + m0 + mm)*256 + hh*32 + d] = acc[ss][mm];
  }
}

// ---------------------------------------------------------------------------
// K5: channel mixes. Block = (8 samples) x (2 modes); 256 thr.
// ---------------------------------------------------------------------------
__global__ __launch_bounds__(256) void mix1_kernel(const float2* __restrict__ Uf,
                                                   const float4* __restrict__ u1wT,
                                                   const float* __restrict__ s1w,
                                                   float2* __restrict__ U1f, float2* __restrict__ S1f){
  int bid = blockIdx.x;                // 256 = ng(8) x mg(32)
  int mg = bid & 31, n0 = (bid >> 5)*8, m0 = mg*2;
  int tid = threadIdx.x;
  __shared__ float2 s_u[8][2][256];    // [s][mm][c] : 32 KB
  __shared__ float  s_w1[32][257];     // padded: o1-major, conflict-free
  for (int it = 0; it < 16; ++it){
    int s = it >> 1, mm = it & 1;
    s_u[s][mm][tid] = Uf[((size_t)(n0+s)*64 + m0 + mm)*256 + tid];
  }
  for (int k = tid; k < 8192; k += 256)
    s_w1[k>>8][k&255] = s1w[k];
  __syncthreads();
  int o1 = tid & 31, mm = (tid >> 5) & 1, sh = tid >> 6;   // sh in 0..3
  int m = m0 + mm, sA = sh*2, sB = sh*2+1;
  const float4* wp = u1wT + (size_t)m*8192 + o1;
  float2 au0 = f2(0,0), au1 = f2(0,0), as0 = f2(0,0), as1 = f2(0,0);
  #pragma unroll 4
  for (int c = 0; c < 256; ++c){
    float4 w = wp[(size_t)c*32];
    float sw = s_w1[o1][c];
    float2 uA = s_u[sA][mm][c];
    float2 uB = s_u[sB][mm][c];
    au0.x += uA.x*w.x - uA.y*w.y;  au0.y += uA.x*w.z + uA.y*w.w;
    au1.x += uB.x*w.x - uB.y*w.y;  au1.y += uB.x*w.z + uB.y*w.w;
    as0.x += uA.x*sw;  as0.y += uA.y*sw;
    as1.x += uB.x*sw;  as1.y += uB.y*sw;
  }
  size_t obA = ((size_t)(n0+sA)*32 + o1)*64 + m;
  size_t obB = ((size_t)(n0+sB)*32 + o1)*64 + m;
  U1f[obA] = au0; S1f[obA] = as0;
  U1f[obB] = au1; S1f[obB] = as1;
}

// ---------------------------------------------------------------------------
// K6: Xg = DFT8x8( gelu( irfft(U1f) ) ); also stores gelu field g to global.
// ---------------------------------------------------------------------------
__global__ __launch_bounds__(512) void xg_kernel(const float2* __restrict__ U1f,
                                                 float2* __restrict__ Xg,
                                                 float* __restrict__ g){
  int f0 = blockIdx.x*2, tid = threadIdx.x;
  __shared__ float2 s_e[64][8];
  __shared__ float2 s_eT[8][64];
  __shared__ float2 s_gu[2][64];
  __shared__ float2 s_tu[2][64][8];    // aliased as s_a1 after phase B
  __shared__ float  s_fld[2][64*68];
  { int a = tid >> 3, b = tid & 7; float2 v = c_tw[(a*b) & 63]; s_e[a][b] = v; s_eT[b][a] = v; }
  if (tid < 128) ((float2*)s_gu)[tid] = U1f[(size_t)f0*NM + tid];
  __syncthreads();
  for (int o = tid; o < 1024; o += 512){
    int fl = o >> 9, r = o & 511, y = r >> 3, kx = r & 7;
    float wf = (kx ? 2.0f : 1.0f) * (1.0f/4096.0f);
    float a0=0.f, b0=0.f, a1=0.f, b1=0.f;
    for (int ky = 0; ky < 4; ++ky){
      float2 cs = s_e[y][ky];
      float2 gu = s_gu[fl][ky*8+kx];
      a0 += gu.x*cs.x - gu.y*cs.y;
      b0 += gu.x*cs.y + gu.y*cs.x;
    }
    for (int ky = 4; ky < 8; ++ky){
      float2 cs = s_e[y][ky];
      float2 gu = s_gu[fl][ky*8+kx];
      a1 += gu.x*cs.x - gu.y*cs.y;
      b1 += gu.x*cs.y + gu.y*cs.x;
    }
    s_tu[fl][y][kx] = f2((a0+a1)*wf, (b0+b1)*wf);
  }
  __syncthreads();
  int xx = tid & 63;
  float2 ce[8];
  #pragma unroll
  for (int k = 0; k < 8; ++k) ce[k] = s_eT[k][xx];
  float* g0p = g + (size_t)f0*NPIX;
  for (int i = 0; i < 8; ++i){
    int p = i*512 + tid, y = p >> 6;   // wave-uniform y
    const float4* tp0 = (const float4*)&s_tu[0][y][0];
    const float4* tp1 = (const float4*)&s_tu[1][y][0];
    float4 a0=tp0[0], a1=tp0[1], a2=tp0[2], a3=tp0[3];
    float4 b0=tp1[0], b1=tp1[1], b2=tp1[2], b3=tp1[3];
    float h0 = a0.x*ce[0].x - a0.y*ce[0].y + a0.z*ce[1].x - a0.w*ce[1].y
             + a1.x*ce[2].x - a1.y*ce[2].y + a1.z*ce[3].x - a1.w*ce[3].y;
    float h1 = a2.x*ce[4].x - a2.y*ce[4].y + a2.z*ce[5].x - a2.w*ce[5].y
             + a3.x*ce[6].x - a3.y*ce[6].y + a3.z*ce[7].x - a3.w*ce[7].y;
    float k0 = b0.x*ce[0].x - b0.y*ce[0].y + b0.z*ce[1].x - b0.w*ce[1].y
             + b1.x*ce[2].x - b1.y*ce[2].y + b1.z*ce[3].x - b1.w*ce[3].y;
    float k1 = b2.x*ce[4].x - b2.y*ce[4].y + b2.z*ce[5].x - b2.w*ce[5].y
             + b3.x*ce[6].x - b3.y*ce[6].y + b3.z*ce[7].x - b3.w*ce[7].y;
    float v0 = h0 + h1, v1 = k0 + k1;
    float ga = 0.5f * v0 * (1.0f + erff(v0 * 0.70710678f));
    float gb = 0.5f * v1 * (1.0f + erff(v1 * 0.70710678f));
    s_fld[0][y*68 + xx] = ga;
    s_fld[1][y*68 + xx] = gb;
    g0p[p] = ga;
    g0p[NPIX + p] = gb;
  }
  __syncthreads();
  float2 (*s_a1)[64][8] = s_tu;
  for (int o = tid; o < 1024; o += 512){
    int fl = o >> 9, r = o & 511, y = r >> 3, kx = r & 7;
    const float4* row = (const float4*)&s_fld[fl][y*68];
    float sr0=0.f, si0=0.f, sr1=0.f, si1=0.f;
    for (int x4 = 0; x4 < 8; ++x4){
      float4 v = row[x4];
      int xb = x4*4;
      float2 c0 = s_e[xb+0][kx], c1 = s_e[xb+1][kx];
      float2 c2 = s_e[xb+2][kx], c3 = s_e[xb+3][kx];
      sr0 += v.x*c0.x + v.y*c1.x + v.z*c2.x + v.w*c3.x;
      si0 -= v.x*c0.y + v.y*c1.y + v.z*c2.y + v.w*c3.y;
    }
    for (int x4 = 8; x4 < 16; ++x4){
      float4 v = row[x4];
      int xb = x4*4;
      float2 c0 = s_e[xb+0][kx], c1 = s_e[xb+1][kx];
      float2 c2 = s_e[xb+2][kx], c3 = s_e[xb+3][kx];
      sr1 += v.x*c0.x + v.y*c1.x + v.z*c2.x + v.w*c3.x;
      si1 -= v.x*c0.y + v.y*c1.y + v.z*c2.y + v.w*c3.y;
    }
    s_a1[fl][y][kx] = f2(sr0+sr1, si0+si1);
  }
  __syncthreads();
  if (tid < 128){
    int fl = tid >> 6, t6 = tid & 63;
    int ky = t6 >> 3, kx = t6 & 7;
    float sr0=0.f, si0=0.f, sr1=0.f, si1=0.f;
    for (int y = 0; y < 32; ++y){
      float2 a = s_a1[fl][y][kx];
      float2 cs = s_e[y][ky];
      sr0 += a.x*cs.x + a.y*cs.y;
      si0 += a.y*cs.x - a.x*cs.y;
    }
    for (int y = 32; y < 64; ++y){
      float2 a = s_a1[fl][y][kx];
      float2 cs = s_e[y][ky];
      sr1 += a.x*cs.x + a.y*cs.y;
      si1 += a.y*cs.x - a.x*cs.y;
    }
    Xg[(size_t)(f0+fl)*NM + t6] = f2(sr0+sr1, si0+si1);
  }
}

// ---------------------------------------------------------------------------
// K7a: per-sample output spectrum; s2w*s1b constant folded into DC mode.
// ---------------------------------------------------------------------------
__global__ __launch_bounds__(256) void final_spec_kernel(const float2* __restrict__ S1f,
                                                         const float2* __restrict__ Xg,
                                                         const float* __restrict__ u2wr, const float* __restrict__ u2wi,
                                                         const float* __restrict__ s1b,
                                                         const float* __restrict__ s2w,
                                                         float2* __restrict__ OS){
  int n = blockIdx.x, tid = threadIdx.x;
  __shared__ float s_w2[128], s_s1b[32];
  if (tid < 128) s_w2[tid] = s2w[tid];
  else if (tid < 160) s_s1b[tid-128] = s1b[tid-128];
  __syncthreads();
  int o2 = tid >> 6, m = tid & 63;
  float prm = ((m & 7)==0 && m) ? 0.5f : 1.0f;
  float pim = m ? prm : 0.0f;
  float dc = (m == 0) ? 4096.0f : 0.0f;
  float cr = 0.f, ci = 0.f;
  for (int o1 = 0; o1 < 32; ++o1){
    float2 xg = Xg[((size_t)n*32 + o1)*NM + m];
    float2 sf = S1f[((size_t)n*32 + o1)*NM + m];
    float Xr = xg.x + sf.x*prm + dc*s_s1b[o1];
    float Xi = xg.y + sf.y*pim;
    size_t wb = ((size_t)(o1*IN_CH + o2))*NM + m;
    float wr = u2wr[wb], wi = u2wi[wb];
    float sw = s_w2[o2*32 + o1];
    cr += Xr*wr - Xi*wi + sw*sf.x;
    ci += Xr*wi + Xi*wr + sw*sf.y;
  }
  if (m == 0){
    float bs = 0.f;
    for (int c = 0; c < 32; ++c) bs += s_w2[o2*32+c] * s_s1b[c];
    cr += 4096.0f * bs;              // rides the DC mode -> +bs at every pixel
  }
  OS[((size_t)n*IN_CH + o2)*NM + m] = f2(cr, ci);
}

// ---------------------------------------------------------------------------
// K7b: thin pixel kernel: out = irfft(OS) + s2 x g(loaded) + b2.
// ---------------------------------------------------------------------------
__global__ __launch_bounds__(512) void final_kernel(const float* __restrict__ g,
                                                    const float2* __restrict__ OS,
                                                    const float* __restrict__ s2w, const float* __restrict__ s2b,
                                                    float* __restrict__ out){
  int n = blockIdx.x >> 3, tile = blockIdx.x & 7, y0 = tile*8;
  int tid = threadIdx.x;
  __shared__ float2 s_e[64][8];
  __shared__ float2 s_eT[8][64];
  __shared__ float2 s_os[4][64];
  __shared__ float2 s_tmp[4][8][8];
  __shared__ float  s_w2[128], s_b2[4];
  { int a = tid >> 3, b = tid & 7; float2 v = c_tw[(a*b) & 63]; s_e[a][b] = v; s_eT[b][a] = v; }
  if (tid < 256) ((float2*)s_os)[tid] = OS[(size_t)n*256 + tid];
  else if (tid < 384) s_w2[tid-256] = s2w[tid-256];
  else if (tid < 388) s_b2[tid-384] = s2b[tid-384];
  __syncthreads();
  if (tid < 256){
    int o2 = tid >> 6, yy = (tid >> 3) & 7, kx = tid & 7;
    int y = y0 + yy;
    float wf = (kx ? 2.0f : 1.0f) * (1.0f/4096.0f);
    float tr=0.f, ti=0.f;
    for (int ky = 0; ky < 8; ++ky){
      float2 cs = s_e[y][ky];
      float2 gv = s_os[o2][ky*8+kx];
      tr += gv.x*cs.x - gv.y*cs.y;
      ti += gv.x*cs.y + gv.y*cs.x;
    }
    s_tmp[o2][yy][kx] = f2(tr*wf, ti*wf);
  }
  __syncthreads();
  int yy = tid >> 6, xx = tid & 63;
  int p = (y0 + yy)*64 + xx;
  float2 ce[8];
  #pragma unroll
  for (int k = 0; k < 8; ++k) ce[k] = s_eT[k][xx];
  float a0 = s_b2[0], a1 = s_b2[1], a2 = s_b2[2], a3 = s_b2[3];
  const float* gp = g + (size_t)n*HIDC*NPIX + p;
  #pragma unroll 8
  for (int c = 0; c < 32; ++c){
    float gv = gp[(size_t)c*NPIX];
    a0 += s_w2[c]*gv; a1 += s_w2[32+c]*gv; a2 += s_w2[64+c]*gv; a3 += s_w2[96+c]*gv;
  }
  float sp[4];
  #pragma unroll
  for (int o2 = 0; o2 < 4; ++o2){
    const float4* tp = (const float4*)&s_tmp[o2][yy][0];
    float4 t0 = tp[0], t1 = tp[1], t2 = tp[2], t3 = tp[3];
    float h0 = t0.x*ce[0].x - t0.y*ce[0].y + t0.z*ce[1].x - t0.w*ce[1].y
             + t1.x*ce[2].x - t1.y*ce[2].y + t1.z*ce[3].x - t1.w*ce[3].y;
    float h1 = t2.x*ce[4].x - t2.y*ce[4].y + t2.z*ce[5].x - t2.w*ce[5].y
             + t3.x*ce[6].x - t3.y*ce[6].y + t3.z*ce[7].x - t3.w*ce[7].y;
    sp[o2] = h0 + h1;
  }
  float* ob = out + (size_t)n*IN_CH*NPIX;
  ob[p]          = a0 + sp[0];
  ob[NPIX + p]   = a1 + sp[1];
  ob[2*NPIX + p] = a2 + sp[2];
  ob[3*NPIX + p] = a3 + sp[3];
}

extern "C" void kernel_launch(void* const* d_in, const int* in_sizes, int n_in,
                              void* d_out, int out_size, void* d_ws, size_t ws_size,
                              hipStream_t stream) {
  (void)in_sizes; (void)n_in; (void)out_size; (void)ws_size;
  const float* v    = (const float*)d_in[0];
  const float* qwr  = (const float*)d_in[1];
  const float* qwi  = (const float*)d_in[2];
  const float* kwr  = (const float*)d_in[3];
  const float* kwi  = (const float*)d_in[4];
  const float* vwr  = (const float*)d_in[5];
  const float* vwi  = (const float*)d_in[6];
  const float* u1wr = (const float*)d_in[7];
  const float* u1wi = (const float*)d_in[8];
  const float* u2wr = (const float*)d_in[9];
  const float* u2wi = (const float*)d_in[10];
  const float* s1w  = (const float*)d_in[11];
  const float* s1b  = (const float*)d_in[12];
  const float* s2w  = (const float*)d_in[13];
  const float* s2b  = (const float*)d_in[14];
  float* out = (float*)d_out;

  float* ws = (float*)d_ws;
  size_t off = 0;
  float2* Vf   = (float2*)(ws + off); off += (size_t)NS*IN_CH*NM*2;     // 32768
  float2* G2   = (float2*)(ws + off); off += (size_t)65536*2;           // 131072
  float*  Gdc  =          (ws + off); off += 4096;
  float*  A    =          (ws + off); off += 16384;
  float2* Uf   = (float2*)(ws + off); off += (size_t)NS*NM*HD*2;        // 2097152
  float2* U1f  = (float2*)(ws + off); off += (size_t)NS*HIDC*NM*2;      // 262144
  float2* S1f  = (float2*)(ws + off); off += (size_t)NS*HIDC*NM*2;      // 262144
  float2* Xg   = (float2*)(ws + off); off += (size_t)NS*HIDC*NM*2;      // 262144
  float4* u1wT = (float4*)(ws + off); off += (size_t)524288*4;          // 2097152
  float2* vwT  = (float2*)(ws + off); off += (size_t)65536*2;           // 131072
  float2* OS   = (float2*)(ws + off); off += (size_t)NS*IN_CH*NM*2;     // 32768
  float*  gfld =          (ws + off); off += (size_t)NS*HIDC*NPIX;      // 8388608

  prep_dft_kernel<<<1472, 512, 0, stream>>>(v, qwr, qwi, kwr, kwi, vwr, vwi, u1wr, u1wi,
                                            Vf, G2, Gdc, vwT, u1wT);
  attn_kernel<<<512, 256, 0, stream>>>(Vf, G2, Gdc, A);
  uspec_kernel<<<512, 256, 0, stream>>>(Vf, vwT, A, Uf);
  mix1_kernel<<<256, 256, 0, stream>>>(Uf, u1wT, s1w, U1f, S1f);
  xg_kernel<<<1024, 512, 0, stream>>>(U1f, Xg, gfld);
  final_spec_kernel<<<NS, 256, 0, stream>>>(S1f, Xg, u2wr, u2wi, s1b, s2w, OS);
  final_kernel<<<NS*8, 512, 0, stream>>>(gfld, OS, s2w, s2b, out);
}